// Round 2
// baseline (605.571 us; speedup 1.0000x reference)
//
#include <hip/hip_runtime.h>

#define DD 128   // feature dim
#define SCH 4096 // scan chunk (elements per block)

typedef float4 f4;
typedef __attribute__((ext_vector_type(8))) short bf16x8;
typedef __attribute__((ext_vector_type(4))) float f32x4;

__device__ __forceinline__ short toBf(float f) {
    unsigned u = __float_as_uint(f);
    u += 0x7fff + ((u >> 16) & 1);   // RNE
    return (short)(u >> 16);
}
__device__ __forceinline__ float bf2f(unsigned short u) {
    return __uint_as_float(((unsigned)u) << 16);
}

// ---------------- setup: flat global-atomic counting sort over M = T*N buckets ----------------

__global__ __launch_bounds__(1024) void kZero(int* __restrict__ p, int n) {
    int i = blockIdx.x * 1024 + threadIdx.x;
    if (i < n) p[i] = 0;
}

// count: cntD[d*T+k]++, cntS[k*N+s]++  (fire-and-forget atomics, no return value)
__global__ __launch_bounds__(256) void kCount(const int* __restrict__ ei, const int* __restrict__ ea,
                                              int E, int N, int T,
                                              int* __restrict__ cntD, int* __restrict__ cntS) {
    int stride = gridDim.x * 256;
    for (int e = blockIdx.x * 256 + threadIdx.x; e < E; e += stride) {
        int s = ei[e], d = ei[E + e], k = ea[e] - 1;
        atomicAdd(&cntD[d * T + k], 1);
        atomicAdd(&cntS[k * N + s], 1);
    }
}

// scan level 1: per-block sums of cntD chunks
__global__ __launch_bounds__(1024) void kS1(const int* __restrict__ cntD, int M, int* __restrict__ bsum) {
    __shared__ int sh[1024];
    int b = blockIdx.x, tid = threadIdx.x;
    int i0 = b * SCH + tid * 4;
    int s = 0;
#pragma unroll
    for (int j = 0; j < 4; j++) { int i = i0 + j; if (i < M) s += cntD[i]; }
    sh[tid] = s; __syncthreads();
    for (int off = 512; off; off >>= 1) {
        if (tid < off) sh[tid] += sh[tid + off];
        __syncthreads();
    }
    if (tid == 0) bsum[b] = sh[0];
}

// scan level 2: exclusive scan of block sums (nb <= 1024)
__global__ __launch_bounds__(1024) void kS2(int* __restrict__ bsum, int nb) {
    __shared__ int sh[1024];
    int tid = threadIdx.x;
    sh[tid] = (tid < nb) ? bsum[tid] : 0;
    __syncthreads();
    for (int off = 1; off < 1024; off <<= 1) {
        int add = (tid >= off) ? sh[tid - off] : 0;
        __syncthreads(); sh[tid] += add; __syncthreads();
    }
    if (tid < nb) bsum[tid] = (tid == 0) ? 0 : sh[tid - 1];
}

// scan level 3: per-element exclusive prefix -> rowptr & ofs; in-place cnt -> rsqrt for both arrays
__global__ __launch_bounds__(1024) void kS3(int* __restrict__ cntD_isdD2,  // int in, float out (same mem)
                                            int* __restrict__ cntS_isdS,   // int in, float out (same mem)
                                            const int* __restrict__ bsum, int M, int E,
                                            int* __restrict__ rowptr, int* __restrict__ ofs) {
    __shared__ int sh[1024];
    int b = blockIdx.x, tid = threadIdx.x;
    int i0 = b * SCH + tid * 4;
    int c[4];
    int s = 0;
#pragma unroll
    for (int j = 0; j < 4; j++) {
        int i = i0 + j;
        c[j] = (i < M) ? cntD_isdD2[i] : 0;
        s += c[j];
    }
    sh[tid] = s; __syncthreads();
    for (int off = 1; off < 1024; off <<= 1) {
        int add = (tid >= off) ? sh[tid - off] : 0;
        __syncthreads(); sh[tid] += add; __syncthreads();
    }
    int run = bsum[b] + sh[tid] - s;   // exclusive prefix of this thread's first element
    float* isdD2 = (float*)cntD_isdD2;
    float* isdS  = (float*)cntS_isdS;
#pragma unroll
    for (int j = 0; j < 4; j++) {
        int i = i0 + j;
        if (i < M) {
            rowptr[i] = run;
            ofs[i] = run;
            int cs = cntS_isdS[i];
            isdD2[i] = rsqrtf((float)max(c[j], 1));
            isdS[i]  = rsqrtf((float)max(cs, 1));
            run += c[j];
        }
    }
    if (b == 0 && tid == 0) rowptr[M] = E;
}

// placement: scatter payloads into (dst,k)-bucket order
__global__ __launch_bounds__(256) void kPlace(const int* __restrict__ ei, const int* __restrict__ ea,
                                              int E, int N, int T,
                                              int* __restrict__ ofs, int* __restrict__ ep) {
    int stride = gridDim.x * 256;
    for (int e = blockIdx.x * 256 + threadIdx.x; e < E; e += stride) {
        int s = ei[e], d = ei[E + e], k = ea[e] - 1;
        int pos = atomicAdd(&ofs[d * T + k], 1);
        ep[pos] = (k << 26) | (k * N + s);
    }
}

__global__ void k_prepW(const float* __restrict__ W, ushort* __restrict__ WT, int tot) {
    int i = blockIdx.x * blockDim.x + threadIdx.x;
    if (i >= tot) return;
    int k = i >> 14, rem = i & 16383, j = rem >> 7, d = rem & 127;
    WT[i] = (ushort)toBf(W[(size_t)k * 16384 + (size_t)d * DD + j]);   // WT[k][j][d] = W[k][d][j]
}

__global__ void k_cvt(const float* __restrict__ x, ushort* __restrict__ xb, int n8) {
    int i = blockIdx.x * blockDim.x + threadIdx.x;
    if (i >= n8) return;
    const f4* q = (const f4*)(x + (size_t)i * 8);
    f4 lo = q[0], hi = q[1];
    bf16x8 r;
    r[0] = toBf(lo.x); r[1] = toBf(lo.y); r[2] = toBf(lo.z); r[3] = toBf(lo.w);
    r[4] = toBf(hi.x); r[5] = toBf(hi.y); r[6] = toBf(hi.z); r[7] = toBf(hi.w);
    *(bf16x8*)(xb + (size_t)i * 8) = r;
}

// ------- batched GEMM: H'_k0[N,128](bf16) = diag(isk) * (A_k0 @ W_k0), MFMA -------
// W staged in LDS (32 KB) with 16B-granule XOR swizzle; 256 rows/block, 64 rows/wave.

struct APtrs { const ushort* a0; const ushort* a1; const ushort* a2; const ushort* a3; };

__global__ __launch_bounds__(256) void k_gemm_batch(APtrs ap,
                                                    const ushort* __restrict__ WTb,
                                                    const float* __restrict__ iskb,
                                                    ushort* __restrict__ Hb, int N) {
    __shared__ ushort lW[128 * 128];   // 32 KB
    int k0 = blockIdx.y;
    const ushort* A = (k0 == 0) ? ap.a0 : (k0 == 1) ? ap.a1 : (k0 == 2) ? ap.a2 : ap.a3;
    const ushort* WT = WTb + (size_t)k0 * DD * DD;
    const float* isk = iskb + (size_t)k0 * N;
    ushort* H = Hb + (size_t)k0 * N * DD;

    int tid = threadIdx.x;
    // stage W: 2048 16B granules, swizzled slot = slot ^ (row&7)
#pragma unroll
    for (int i = 0; i < 8; i++) {
        int g = tid + i * 256;
        int row = g >> 4, slot = g & 15;
        bf16x8 v = *(const bf16x8*)(WT + row * DD + slot * 8);
        *(bf16x8*)(lW + row * DD + (slot ^ (row & 7)) * 8) = v;
    }
    __syncthreads();

    int wave = tid >> 6;
    int lane = tid & 63;
    int rlo = lane & 15;       // A row within strip / C col within 16
    int khi = lane >> 4;       // 0..3
    int r0 = blockIdx.x * 256 + wave * 64;

    f32x4 acc[4][8];
#pragma unroll
    for (int s = 0; s < 4; s++)
#pragma unroll
        for (int j = 0; j < 8; j++) acc[s][j] = (f32x4){0.f, 0.f, 0.f, 0.f};

    int ca[4];
#pragma unroll
    for (int s = 0; s < 4; s++) {
        int r = r0 + s * 16 + rlo;
        ca[s] = r < N ? r : N - 1;
    }

#pragma unroll
    for (int kk = 0; kk < 4; kk++) {
        int d0 = kk * 32 + khi * 8;
        bf16x8 a[4];
#pragma unroll
        for (int s = 0; s < 4; s++)
            a[s] = *(const bf16x8*)(A + (size_t)ca[s] * DD + d0);
        int q = kk * 4 + khi;   // 16B slot index along d
#pragma unroll
        for (int cg = 0; cg < 8; cg++) {
            int row = cg * 16 + rlo;
            bf16x8 b = *(const bf16x8*)(lW + row * DD + (q ^ (rlo & 7)) * 8);
#pragma unroll
            for (int s = 0; s < 4; s++)
                acc[s][cg] = __builtin_amdgcn_mfma_f32_16x16x32_bf16(a[s], b, acc[s][cg], 0, 0, 0);
        }
    }

#pragma unroll
    for (int s = 0; s < 4; s++) {
#pragma unroll
        for (int r = 0; r < 4; r++) {
            int row = r0 + s * 16 + khi * 4 + r;
            if (row < N) {
                float sc = isk[row];
#pragma unroll
                for (int cg = 0; cg < 8; cg++)
                    H[(size_t)row * DD + cg * 16 + rlo] = (ushort)toBf(sc * acc[s][cg][r]);
            }
        }
    }
}

// ------- fused per-layer: gather-sum over contiguous segment; out = l2norm(hist + relu(acc)) -------

__device__ __forceinline__ float selw(float w0, float w1, float w2, float w3, int k) {
    float a = (k & 1) ? w1 : w0;
    float b = (k & 1) ? w3 : w2;
    return (k & 2) ? b : a;
}

__global__ __launch_bounds__(256) void k_agg_fin(
        const ushort* __restrict__ H,        // T*N rows of 128 bf16, row idx = k*N+src
        const int* __restrict__ ep,          // packed payloads, (dst,k)-bucket order
        const int* __restrict__ rp,          // M+1 rowptr, bucket = d*T+k
        const float* __restrict__ isdD2,     // M, d*T+k
        const float* __restrict__ nu, int t, int T, int nk,
        const ushort* __restrict__ hp,       // residual input (bf16)
        ushort* __restrict__ hnB,            // bf16 hist output (t < T-1)
        float* __restrict__ outF,            // f32 output (t == T-1), else null
        int N) {
    int node = (blockIdx.x * blockDim.x + threadIdx.x) >> 5;
    if (node >= N) return;
    int lane = threadIdx.x & 31;
    int rbase = node * T;
    int b0 = rp[rbase], b1 = rp[rbase + nk];

    float w0 = nu[t] * isdD2[rbase];
    float w1 = (1 < nk) ? nu[T + t]     * isdD2[rbase + 1] : 0.f;
    float w2 = (2 < nk) ? nu[2 * T + t] * isdD2[rbase + 2] : 0.f;
    float w3 = (3 < nk) ? nu[3 * T + t] * isdD2[rbase + 3] : 0.f;

    const char* Hc = (const char*)H;
    unsigned lb = (unsigned)lane << 3;   // byte offset of this lane's 8B within a 256B row

    float sx = 0.f, sy = 0.f, sz = 0.f, sw = 0.f;
    int e = b0;

// decode payload -> 32-bit byte offset + coefficient
#define DEC(P, O, C) \
    O = ((((unsigned)(P)) & 0x3FFFFFFu) << 8) | lb; \
    C = selw(w0, w1, w2, w3, (P) >> 26);

// accumulate one gathered uint2 (4 bf16) with coefficient C
#define ACC(G, C) { \
    float f0 = __uint_as_float((G).x << 16); \
    float f1 = __uint_as_float((G).x & 0xffff0000u); \
    float f2 = __uint_as_float((G).y << 16); \
    float f3 = __uint_as_float((G).y & 0xffff0000u); \
    sx = fmaf((C), f0, sx); sy = fmaf((C), f1, sy); \
    sz = fmaf((C), f2, sz); sw = fmaf((C), f3, sw); }

    // 8-deep main loop: 8 payload loads, then 8 gathers in flight (2 KB/group)
    for (; e + 7 < b1; e += 8) {
        int p0 = ep[e],     p1 = ep[e + 1], p2 = ep[e + 2], p3 = ep[e + 3];
        int p4 = ep[e + 4], p5 = ep[e + 5], p6 = ep[e + 6], p7 = ep[e + 7];
        unsigned o0, o1, o2, o3, o4, o5, o6, o7;
        float c0, c1, c2, c3, c4, c5, c6, c7;
        DEC(p0, o0, c0) DEC(p1, o1, c1) DEC(p2, o2, c2) DEC(p3, o3, c3)
        DEC(p4, o4, c4) DEC(p5, o5, c5) DEC(p6, o6, c6) DEC(p7, o7, c7)
        uint2 g0 = *(const uint2*)(Hc + o0);
        uint2 g1 = *(const uint2*)(Hc + o1);
        uint2 g2 = *(const uint2*)(Hc + o2);
        uint2 g3 = *(const uint2*)(Hc + o3);
        uint2 g4 = *(const uint2*)(Hc + o4);
        uint2 g5 = *(const uint2*)(Hc + o5);
        uint2 g6 = *(const uint2*)(Hc + o6);
        uint2 g7 = *(const uint2*)(Hc + o7);
        ACC(g0, c0) ACC(g1, c1) ACC(g2, c2) ACC(g3, c3)
        ACC(g4, c4) ACC(g5, c5) ACC(g6, c6) ACC(g7, c7)
    }
    // 4-deep tier
    if (e + 3 < b1) {
        int p0 = ep[e], p1 = ep[e + 1], p2 = ep[e + 2], p3 = ep[e + 3];
        unsigned o0, o1, o2, o3;
        float c0, c1, c2, c3;
        DEC(p0, o0, c0) DEC(p1, o1, c1) DEC(p2, o2, c2) DEC(p3, o3, c3)
        uint2 g0 = *(const uint2*)(Hc + o0);
        uint2 g1 = *(const uint2*)(Hc + o1);
        uint2 g2 = *(const uint2*)(Hc + o2);
        uint2 g3 = *(const uint2*)(Hc + o3);
        ACC(g0, c0) ACC(g1, c1) ACC(g2, c2) ACC(g3, c3)
        e += 4;
    }
    // scalar tail
    for (; e < b1; e++) {
        int p0 = ep[e];
        unsigned o0; float c0;
        DEC(p0, o0, c0)
        uint2 g0 = *(const uint2*)(Hc + o0);
        ACC(g0, c0)
    }
#undef DEC
#undef ACC

    unsigned nodeOff = ((unsigned)node << 8) | lb;
    uint2 hv = *(const uint2*)((const char*)hp + nodeOff);
    float vx = __uint_as_float(hv.x << 16)         + fmaxf(sx, 0.f);
    float vy = __uint_as_float(hv.x & 0xffff0000u) + fmaxf(sy, 0.f);
    float vz = __uint_as_float(hv.y << 16)         + fmaxf(sz, 0.f);
    float vw = __uint_as_float(hv.y & 0xffff0000u) + fmaxf(sw, 0.f);
    float ss = vx * vx + vy * vy + vz * vz + vw * vw;
#pragma unroll
    for (int off = 16; off; off >>= 1) ss += __shfl_xor(ss, off, 32);
    float inv = 1.f / fmaxf(sqrtf(ss), 1e-12f);
    vx *= inv; vy *= inv; vz *= inv; vw *= inv;
    if (outF) {
        f4 o; o.x = vx; o.y = vy; o.z = vz; o.w = vw;
        *(f4*)((char*)outF + (((size_t)node << 9) | ((size_t)lane << 4))) = o;
    } else {
        uint lo = ((unsigned)(unsigned short)toBf(vx)) | (((unsigned)(unsigned short)toBf(vy)) << 16);
        uint hi = ((unsigned)(unsigned short)toBf(vz)) | (((unsigned)(unsigned short)toBf(vw)) << 16);
        uint2 ob; ob.x = lo; ob.y = hi;
        *(uint2*)((char*)hnB + nodeOff) = ob;
    }
}

// ---------------- driver ----------------

extern "C" void kernel_launch(void* const* d_in, const int* in_sizes, int n_in,
                              void* d_out, int out_size, void* d_ws, size_t ws_size,
                              hipStream_t stream) {
    const float* x  = (const float*)d_in[0];
    const int*   ei = (const int*)d_in[1];
    const int*   ea = (const int*)d_in[2];
    const float* W  = (const float*)d_in[3];
    const float* nu = (const float*)d_in[4];
    float* out = (float*)d_out;

    int N = in_sizes[0] / DD;
    int E = in_sizes[1] / 2;
    int T = in_sizes[3] / (DD * DD);
    int M = T * N;
    size_t ND = (size_t)N * DD;

    int nbS = (M + SCH - 1) / SCH;
    if (nbS > 1024) return;   // scan level-2 capacity guard

    // workspace layout
    float*  isdS  = (float*)d_ws;            // M f32 (counts -> rsqrt deg_src, k-major k*N+s)
    float*  isdD2 = isdS + M;                // M f32 (counts -> rsqrt deg_dst, dst-major d*T+k)
    ushort* xb    = (ushort*)(isdD2 + M);    // ND bf16
    ushort* h1b   = xb + ND;                 // ND bf16
    ushort* h2b   = h1b + ND;                // ND bf16
    ushort* h3b   = h2b + ND;                // ND bf16
    ushort* Hb    = h3b + ND;                // T*ND bf16 (pre-scaled H'_k)
    ushort* WT    = Hb + (size_t)T * ND;     // T*128*128 bf16
    int* rowptr   = (int*)(WT + (size_t)T * DD * DD);  // M+1
    int* ep       = rowptr + M + 1;          // E
    // setup scratch aliases Hb (setup strictly precedes GEMM writes)
    int* ofs  = (int*)Hb;                    // M running offsets
    int* bsum = ofs + M;                     // nbS block sums

    size_t req = sizeof(float) * 2 * (size_t)M
               + sizeof(ushort) * ((size_t)(4 + T) * ND + (size_t)T * DD * DD)
               + sizeof(int) * ((size_t)M + 1 + (size_t)E + 64);
    if (ws_size < req) return;
    size_t scratch = sizeof(int) * ((size_t)M + nbS + 64);
    if (scratch > sizeof(ushort) * (size_t)T * ND) return;

    kZero<<<(2 * M + 1023) / 1024, 1024, 0, stream>>>((int*)isdS, 2 * M);
    kCount<<<2048, 256, 0, stream>>>(ei, ea, E, N, T, (int*)isdD2, (int*)isdS);
    kS1<<<nbS, 1024, 0, stream>>>((int*)isdD2, M, bsum);
    kS2<<<1, 1024, 0, stream>>>(bsum, nbS);
    kS3<<<nbS, 1024, 0, stream>>>((int*)isdD2, (int*)isdS, bsum, M, E, rowptr, ofs);
    kPlace<<<2048, 256, 0, stream>>>(ei, ea, E, N, T, ofs, ep);
    k_prepW<<<(T * DD * DD + 255) / 256, 256, 0, stream>>>(W, WT, T * DD * DD);
    k_cvt<<<((int)(ND / 8) + 255) / 256, 256, 0, stream>>>(x, xb, (int)(ND / 8));

    const ushort* histB[4] = {xb, h1b, h2b, h3b};

    int nodeBlocks = ((size_t)N * 32 + 255) / 256;
    int gemmBlocks = (N + 255) / 256;

    for (int t = 0; t < T; t++) {
        APtrs ap;
        ap.a0 = histB[t];
        ap.a1 = (t >= 1) ? histB[t - 1] : histB[0];
        ap.a2 = (t >= 2) ? histB[t - 2] : histB[0];
        ap.a3 = (t >= 3) ? histB[t - 3] : histB[0];
        dim3 grid(gemmBlocks, t + 1);
        k_gemm_batch<<<grid, 256, 0, stream>>>(ap, WT, isdS, Hb, N);

        bool lastL = (t == T - 1);
        k_agg_fin<<<nodeBlocks, 256, 0, stream>>>(Hb, ep, rowptr, isdD2,
                                                  nu, t, T, t + 1, histB[t],
                                                  lastL ? nullptr : (ushort*)histB[t + 1],
                                                  lastL ? out : nullptr, N);
    }
}

// Round 3
// 480.889 us; speedup vs baseline: 1.2593x; 1.2593x over previous
//
#include <hip/hip_runtime.h>

#define DD 128   // feature dim
#define NP 256   // node partitions
#define EB 8192  // edges per binning block

typedef float4 f4;
typedef __attribute__((ext_vector_type(8))) short bf16x8;
typedef __attribute__((ext_vector_type(4))) float f32x4;

__device__ __forceinline__ short toBf(float f) {
    unsigned u = __float_as_uint(f);
    u += 0x7fff + ((u >> 16) & 1);   // RNE
    return (short)(u >> 16);
}
__device__ __forceinline__ float bf2f(unsigned short u) {
    return __uint_as_float(((unsigned)u) << 16);
}

// ---------------- setup: LDS-binned counting sort (no global atomics) ----------------

__global__ __launch_bounds__(1024) void kA(const int* __restrict__ ei, int E, int PSZ, int nbA,
                                           int* __restrict__ cntB_D, int* __restrict__ cntB_S) {
    __shared__ int hd[NP], hs[NP];
    int tid = threadIdx.x;
    if (tid < NP) { hd[tid] = 0; hs[tid] = 0; }
    __syncthreads();
    int base = blockIdx.x * EB;
    int lim = min(base + EB, E);
    for (int e = base + tid; e < lim; e += 1024) {
        int s = ei[e], d = ei[E + e];
        atomicAdd(&hs[s / PSZ], 1);
        atomicAdd(&hd[d / PSZ], 1);
    }
    __syncthreads();
    if (tid < NP) {
        cntB_D[tid * nbA + blockIdx.x] = hd[tid];
        cntB_S[tid * nbA + blockIdx.x] = hs[tid];
    }
}

// fused double scan: blockIdx.x==0 -> D array, ==1 -> S array
__global__ __launch_bounds__(1024) void kB(int* __restrict__ cntB_D, int* __restrict__ cntB_S,
                                           int L, int nbA,
                                           int* __restrict__ partStartD, int* __restrict__ partStartS,
                                           int E) {
    int* cntB = (blockIdx.x == 0) ? cntB_D : cntB_S;
    int* partStart = (blockIdx.x == 0) ? partStartD : partStartS;
    __shared__ int sh[1024];
    int tid = threadIdx.x;
    int CH = (L + 1023) / 1024;
    int b0 = tid * CH, b1 = min(b0 + CH, L);
    int s = 0;
    for (int i = b0; i < b1; i++) s += cntB[i];
    sh[tid] = s; __syncthreads();
    for (int off = 1; off < 1024; off <<= 1) {
        int add = (tid >= off) ? sh[tid - off] : 0;
        __syncthreads(); sh[tid] += add; __syncthreads();
    }
    int run = (tid == 0) ? 0 : sh[tid - 1];
    for (int i = b0; i < b1; i++) {
        int v = cntB[i];
        cntB[i] = run;
        if (i % nbA == 0) partStart[i / nbA] = run;
        run += v;
    }
    if (tid == 0) partStart[NP] = E;
}

__global__ __launch_bounds__(1024) void kC(const int* __restrict__ ei, const int* __restrict__ ea,
                                           int E, int N, int T, int PSZ, int nbA,
                                           const int* __restrict__ cntB_D, const int* __restrict__ cntB_S,
                                           int2* __restrict__ binD, int* __restrict__ binS) {
    __shared__ int pd[NP], ps[NP];
    int tid = threadIdx.x, b = blockIdx.x;
    if (tid < NP) {
        pd[tid] = cntB_D[tid * nbA + b];
        ps[tid] = cntB_S[tid * nbA + b];
    }
    __syncthreads();
    int base = b * EB;
    int lim = min(base + EB, E);
    for (int e = base + tid; e < lim; e += 1024) {
        int s = ei[e], d = ei[E + e], k = ea[e] - 1;
        int dp = d / PSZ, sp = s / PSZ;
        int posD = atomicAdd(&pd[dp], 1);
        binD[posD] = make_int2((d - dp * PSZ) * T + k, (k << 26) | (k * N + s));
        int posS = atomicAdd(&ps[sp], 1);
        binS[posS] = (s - sp * PSZ) * T + k;
    }
}

// fused kD (dst buckets -> rowptr/isdD2/ep) + kE (src degree -> isdS):
// blocks [0,NP) do D-role partition p=b; blocks [NP,2*NP) do S-role partition p=b-NP.
__global__ __launch_bounds__(512) void kDE(const int2* __restrict__ binD,
                                           const int* __restrict__ binS,
                                           const int* __restrict__ partStartD,
                                           const int* __restrict__ partStartS,
                                           int N, int T, int PSZ, int M, int E,
                                           int* __restrict__ rowptr, float* __restrict__ isdD2,
                                           int* __restrict__ ep, float* __restrict__ isdS) {
    __shared__ int cnt[4096];
    __shared__ int part[512];
    int b = blockIdx.x, tid = threadIdx.x;
    int nloc = PSZ * T;
    for (int i = tid; i < nloc; i += 512) cnt[i] = 0;
    __syncthreads();
    if (b < NP) {
        int p = b;
        int b0 = partStartD[p], b1 = partStartD[p + 1];
        for (int e = b0 + tid; e < b1; e += 512) atomicAdd(&cnt[binD[e].x], 1);
        __syncthreads();
        int CH = (nloc + 511) / 512;
        int c0 = tid * CH, c1 = min(c0 + CH, nloc);
        int s = 0;
        for (int i = c0; i < c1; i++) s += cnt[i];
        part[tid] = s; __syncthreads();
        for (int off = 1; off < 512; off <<= 1) {
            int add = (tid >= off) ? part[tid - off] : 0;
            __syncthreads(); part[tid] += add; __syncthreads();
        }
        int run = ((tid == 0) ? 0 : part[tid - 1]) + b0;
        int gb_base = p * PSZ * T;
        for (int i = c0; i < c1; i++) {
            int v = cnt[i];
            cnt[i] = run;
            int gb = gb_base + i;
            if (gb < M) {
                rowptr[gb] = run;
                isdD2[gb] = rsqrtf((float)max(v, 1));
            }
            run += v;
        }
        __syncthreads();
        for (int e = b0 + tid; e < b1; e += 512) {
            int2 v = binD[e];
            int pos = atomicAdd(&cnt[v.x], 1);
            ep[pos] = v.y;
        }
        if (p == 0 && tid == 0) rowptr[M] = E;
    } else {
        int p = b - NP;
        int b0 = partStartS[p], b1 = partStartS[p + 1];
        for (int e = b0 + tid; e < b1; e += 512) atomicAdd(&cnt[binS[e]], 1);
        __syncthreads();
        int s0 = p * PSZ;
        for (int i = tid; i < nloc; i += 512) {
            int sl = i / T, k = i - sl * T;
            int snode = s0 + sl;
            if (snode < N) isdS[k * N + snode] = rsqrtf((float)max(cnt[i], 1));
        }
    }
}

__global__ void k_prepW(const float* __restrict__ W, ushort* __restrict__ WT, int tot) {
    int i = blockIdx.x * blockDim.x + threadIdx.x;
    if (i >= tot) return;
    int k = i >> 14, rem = i & 16383, j = rem >> 7, d = rem & 127;
    WT[i] = (ushort)toBf(W[(size_t)k * 16384 + (size_t)d * DD + j]);   // WT[k][j][d] = W[k][d][j]
}

__global__ void k_cvt(const float* __restrict__ x, ushort* __restrict__ xb, int n8) {
    int i = blockIdx.x * blockDim.x + threadIdx.x;
    if (i >= n8) return;
    const f4* q = (const f4*)(x + (size_t)i * 8);
    f4 lo = q[0], hi = q[1];
    bf16x8 r;
    r[0] = toBf(lo.x); r[1] = toBf(lo.y); r[2] = toBf(lo.z); r[3] = toBf(lo.w);
    r[4] = toBf(hi.x); r[5] = toBf(hi.y); r[6] = toBf(hi.z); r[7] = toBf(hi.w);
    *(bf16x8*)(xb + (size_t)i * 8) = r;
}

// ------- batched GEMM: H'_k0[N,128](bf16) = diag(isk) * (A_k0 @ W_k0), MFMA -------
// W staged in LDS (32 KB) with 16B-granule XOR swizzle; 256 rows/block, 64 rows/wave.

struct APtrs { const ushort* a0; const ushort* a1; const ushort* a2; const ushort* a3; };

__global__ __launch_bounds__(256) void k_gemm_batch(APtrs ap,
                                                    const ushort* __restrict__ WTb,
                                                    const float* __restrict__ iskb,
                                                    ushort* __restrict__ Hb, int N) {
    __shared__ ushort lW[128 * 128];   // 32 KB
    int k0 = blockIdx.y;
    const ushort* A = (k0 == 0) ? ap.a0 : (k0 == 1) ? ap.a1 : (k0 == 2) ? ap.a2 : ap.a3;
    const ushort* WT = WTb + (size_t)k0 * DD * DD;
    const float* isk = iskb + (size_t)k0 * N;
    ushort* H = Hb + (size_t)k0 * N * DD;

    int tid = threadIdx.x;
    // stage W: 2048 16B granules, swizzled slot = slot ^ (row&7)
#pragma unroll
    for (int i = 0; i < 8; i++) {
        int g = tid + i * 256;
        int row = g >> 4, slot = g & 15;
        bf16x8 v = *(const bf16x8*)(WT + row * DD + slot * 8);
        *(bf16x8*)(lW + row * DD + (slot ^ (row & 7)) * 8) = v;
    }
    __syncthreads();

    int wave = tid >> 6;
    int lane = tid & 63;
    int rlo = lane & 15;       // A row within strip / C col within 16
    int khi = lane >> 4;       // 0..3
    int r0 = blockIdx.x * 256 + wave * 64;

    f32x4 acc[4][8];
#pragma unroll
    for (int s = 0; s < 4; s++)
#pragma unroll
        for (int j = 0; j < 8; j++) acc[s][j] = (f32x4){0.f, 0.f, 0.f, 0.f};

    int ca[4];
#pragma unroll
    for (int s = 0; s < 4; s++) {
        int r = r0 + s * 16 + rlo;
        ca[s] = r < N ? r : N - 1;
    }

#pragma unroll
    for (int kk = 0; kk < 4; kk++) {
        int d0 = kk * 32 + khi * 8;
        bf16x8 a[4];
#pragma unroll
        for (int s = 0; s < 4; s++)
            a[s] = *(const bf16x8*)(A + (size_t)ca[s] * DD + d0);
        int q = kk * 4 + khi;   // 16B slot index along d
#pragma unroll
        for (int cg = 0; cg < 8; cg++) {
            int row = cg * 16 + rlo;
            bf16x8 b = *(const bf16x8*)(lW + row * DD + (q ^ (rlo & 7)) * 8);
#pragma unroll
            for (int s = 0; s < 4; s++)
                acc[s][cg] = __builtin_amdgcn_mfma_f32_16x16x32_bf16(a[s], b, acc[s][cg], 0, 0, 0);
        }
    }

#pragma unroll
    for (int s = 0; s < 4; s++) {
#pragma unroll
        for (int r = 0; r < 4; r++) {
            int row = r0 + s * 16 + khi * 4 + r;
            if (row < N) {
                float sc = isk[row];
#pragma unroll
                for (int cg = 0; cg < 8; cg++)
                    H[(size_t)row * DD + cg * 16 + rlo] = (ushort)toBf(sc * acc[s][cg][r]);
            }
        }
    }
}

// ------- fused per-layer: gather-sum over contiguous segment; out = l2norm(hist + relu(acc)) -------

__device__ __forceinline__ float selw(float w0, float w1, float w2, float w3, int k) {
    float a = (k & 1) ? w1 : w0;
    float b = (k & 1) ? w3 : w2;
    return (k & 2) ? b : a;
}

__global__ __launch_bounds__(256) void k_agg_fin(
        const ushort* __restrict__ H,        // T*N rows of 128 bf16, row idx = k*N+src
        const int* __restrict__ ep,          // packed payloads, (dst,k)-bucket order
        const int* __restrict__ rp,          // M+1 rowptr, bucket = d*T+k
        const float* __restrict__ isdD2,     // M, d*T+k
        const float* __restrict__ nu, int t, int T, int nk,
        const ushort* __restrict__ hp,       // residual input (bf16)
        ushort* __restrict__ hnB,            // bf16 hist output (t < T-1)
        float* __restrict__ outF,            // f32 output (t == T-1), else null
        int N) {
    int node = (blockIdx.x * blockDim.x + threadIdx.x) >> 5;
    if (node >= N) return;
    int lane = threadIdx.x & 31;
    int rbase = node * T;
    int b0 = rp[rbase], b1 = rp[rbase + nk];

    float w0 = nu[t] * isdD2[rbase];
    float w1 = (1 < nk) ? nu[T + t]     * isdD2[rbase + 1] : 0.f;
    float w2 = (2 < nk) ? nu[2 * T + t] * isdD2[rbase + 2] : 0.f;
    float w3 = (3 < nk) ? nu[3 * T + t] * isdD2[rbase + 3] : 0.f;

    const char* Hc = (const char*)H;
    unsigned lb = (unsigned)lane << 3;   // byte offset of this lane's 8B within a 256B row

    float sx = 0.f, sy = 0.f, sz = 0.f, sw = 0.f;
    int e = b0;

// decode payload -> 32-bit byte offset + coefficient
#define DEC(P, O, C) \
    O = ((((unsigned)(P)) & 0x3FFFFFFu) << 8) | lb; \
    C = selw(w0, w1, w2, w3, (P) >> 26);

// accumulate one gathered uint2 (4 bf16) with coefficient C
#define ACC(G, C) { \
    float f0 = __uint_as_float((G).x << 16); \
    float f1 = __uint_as_float((G).x & 0xffff0000u); \
    float f2 = __uint_as_float((G).y << 16); \
    float f3 = __uint_as_float((G).y & 0xffff0000u); \
    sx = fmaf((C), f0, sx); sy = fmaf((C), f1, sy); \
    sz = fmaf((C), f2, sz); sw = fmaf((C), f3, sw); }

    // 8-deep main loop: 8 payload loads, then 8 gathers in flight (2 KB/group)
    for (; e + 7 < b1; e += 8) {
        int p0 = ep[e],     p1 = ep[e + 1], p2 = ep[e + 2], p3 = ep[e + 3];
        int p4 = ep[e + 4], p5 = ep[e + 5], p6 = ep[e + 6], p7 = ep[e + 7];
        unsigned o0, o1, o2, o3, o4, o5, o6, o7;
        float c0, c1, c2, c3, c4, c5, c6, c7;
        DEC(p0, o0, c0) DEC(p1, o1, c1) DEC(p2, o2, c2) DEC(p3, o3, c3)
        DEC(p4, o4, c4) DEC(p5, o5, c5) DEC(p6, o6, c6) DEC(p7, o7, c7)
        uint2 g0 = *(const uint2*)(Hc + o0);
        uint2 g1 = *(const uint2*)(Hc + o1);
        uint2 g2 = *(const uint2*)(Hc + o2);
        uint2 g3 = *(const uint2*)(Hc + o3);
        uint2 g4 = *(const uint2*)(Hc + o4);
        uint2 g5 = *(const uint2*)(Hc + o5);
        uint2 g6 = *(const uint2*)(Hc + o6);
        uint2 g7 = *(const uint2*)(Hc + o7);
        ACC(g0, c0) ACC(g1, c1) ACC(g2, c2) ACC(g3, c3)
        ACC(g4, c4) ACC(g5, c5) ACC(g6, c6) ACC(g7, c7)
    }
    // 4-deep tier
    if (e + 3 < b1) {
        int p0 = ep[e], p1 = ep[e + 1], p2 = ep[e + 2], p3 = ep[e + 3];
        unsigned o0, o1, o2, o3;
        float c0, c1, c2, c3;
        DEC(p0, o0, c0) DEC(p1, o1, c1) DEC(p2, o2, c2) DEC(p3, o3, c3)
        uint2 g0 = *(const uint2*)(Hc + o0);
        uint2 g1 = *(const uint2*)(Hc + o1);
        uint2 g2 = *(const uint2*)(Hc + o2);
        uint2 g3 = *(const uint2*)(Hc + o3);
        ACC(g0, c0) ACC(g1, c1) ACC(g2, c2) ACC(g3, c3)
        e += 4;
    }
    // scalar tail
    for (; e < b1; e++) {
        int p0 = ep[e];
        unsigned o0; float c0;
        DEC(p0, o0, c0)
        uint2 g0 = *(const uint2*)(Hc + o0);
        ACC(g0, c0)
    }
#undef DEC
#undef ACC

    unsigned nodeOff = ((unsigned)node << 8) | lb;
    uint2 hv = *(const uint2*)((const char*)hp + nodeOff);
    float vx = __uint_as_float(hv.x << 16)         + fmaxf(sx, 0.f);
    float vy = __uint_as_float(hv.x & 0xffff0000u) + fmaxf(sy, 0.f);
    float vz = __uint_as_float(hv.y << 16)         + fmaxf(sz, 0.f);
    float vw = __uint_as_float(hv.y & 0xffff0000u) + fmaxf(sw, 0.f);
    float ss = vx * vx + vy * vy + vz * vz + vw * vw;
#pragma unroll
    for (int off = 16; off; off >>= 1) ss += __shfl_xor(ss, off, 32);
    float inv = 1.f / fmaxf(sqrtf(ss), 1e-12f);
    vx *= inv; vy *= inv; vz *= inv; vw *= inv;
    if (outF) {
        f4 o; o.x = vx; o.y = vy; o.z = vz; o.w = vw;
        *(f4*)((char*)outF + (((size_t)node << 9) | ((size_t)lane << 4))) = o;
    } else {
        uint lo = ((unsigned)(unsigned short)toBf(vx)) | (((unsigned)(unsigned short)toBf(vy)) << 16);
        uint hi = ((unsigned)(unsigned short)toBf(vz)) | (((unsigned)(unsigned short)toBf(vw)) << 16);
        uint2 ob; ob.x = lo; ob.y = hi;
        *(uint2*)((char*)hnB + nodeOff) = ob;
    }
}

// ---------------- driver ----------------

extern "C" void kernel_launch(void* const* d_in, const int* in_sizes, int n_in,
                              void* d_out, int out_size, void* d_ws, size_t ws_size,
                              hipStream_t stream) {
    const float* x  = (const float*)d_in[0];
    const int*   ei = (const int*)d_in[1];
    const int*   ea = (const int*)d_in[2];
    const float* W  = (const float*)d_in[3];
    const float* nu = (const float*)d_in[4];
    float* out = (float*)d_out;

    int N = in_sizes[0] / DD;
    int E = in_sizes[1] / 2;
    int T = in_sizes[3] / (DD * DD);
    int M = T * N;
    size_t ND = (size_t)N * DD;

    int PSZ = (N + NP - 1) / NP;          // nodes per partition
    if (PSZ * T > 4096) return;           // LDS counter budget guard
    int nbA = (E + EB - 1) / EB;          // binning blocks

    // workspace layout
    float*  isdS  = (float*)d_ws;            // M f32 (k-major, rsqrt deg_src)
    float*  isdD2 = isdS + M;                // M f32 (dst-major d*T+k, rsqrt deg_dst)
    ushort* xb    = (ushort*)(isdD2 + M);    // ND bf16
    ushort* h1b   = xb + ND;                 // ND bf16
    ushort* h2b   = h1b + ND;                // ND bf16
    ushort* h3b   = h2b + ND;                // ND bf16
    ushort* Hb    = h3b + ND;                // T*ND bf16 (pre-scaled H'_k)
    ushort* WT    = Hb + (size_t)T * ND;     // T*128*128 bf16
    int* rowptr   = (int*)(WT + (size_t)T * DD * DD);  // M+1
    int* ep       = rowptr + M + 1;          // E
    // setup scratch aliases Hb (setup strictly precedes GEMM writes)
    int2* binD       = (int2*)Hb;                        // E int2
    int*  binS       = (int*)(binD + E);                 // E
    int*  cntB_D     = binS + E;                         // NP*nbA
    int*  cntB_S     = cntB_D + NP * nbA;                // NP*nbA
    int*  partStartD = cntB_S + NP * nbA;                // NP+1
    int*  partStartS = partStartD + NP + 1;              // NP+1

    size_t req = sizeof(float) * 2 * (size_t)M
               + sizeof(ushort) * ((size_t)(4 + T) * ND + (size_t)T * DD * DD)
               + sizeof(int) * ((size_t)M + 1 + (size_t)E + 64);
    if (ws_size < req) return;
    size_t scratch = sizeof(int) * (3 * (size_t)E + 2 * (size_t)NP * nbA + 2 * (NP + 1));
    if (scratch > sizeof(ushort) * (size_t)T * ND) return;

    kA<<<nbA, 1024, 0, stream>>>(ei, E, PSZ, nbA, cntB_D, cntB_S);
    kB<<<2, 1024, 0, stream>>>(cntB_D, cntB_S, NP * nbA, nbA, partStartD, partStartS, E);
    kC<<<nbA, 1024, 0, stream>>>(ei, ea, E, N, T, PSZ, nbA, cntB_D, cntB_S, binD, binS);
    kDE<<<2 * NP, 512, 0, stream>>>(binD, binS, partStartD, partStartS,
                                    N, T, PSZ, M, E, rowptr, isdD2, ep, isdS);
    k_prepW<<<(T * DD * DD + 255) / 256, 256, 0, stream>>>(W, WT, T * DD * DD);
    k_cvt<<<((int)(ND / 8) + 255) / 256, 256, 0, stream>>>(x, xb, (int)(ND / 8));

    const ushort* histB[4] = {xb, h1b, h2b, h3b};

    int nodeBlocks = ((size_t)N * 32 + 255) / 256;
    int gemmBlocks = (N + 255) / 256;

    for (int t = 0; t < T; t++) {
        APtrs ap;
        ap.a0 = histB[t];
        ap.a1 = (t >= 1) ? histB[t - 1] : histB[0];
        ap.a2 = (t >= 2) ? histB[t - 2] : histB[0];
        ap.a3 = (t >= 3) ? histB[t - 3] : histB[0];
        dim3 grid(gemmBlocks, t + 1);
        k_gemm_batch<<<grid, 256, 0, stream>>>(ap, WT, isdS, Hb, N);

        bool lastL = (t == T - 1);
        k_agg_fin<<<nodeBlocks, 256, 0, stream>>>(Hb, ep, rowptr, isdD2,
                                                  nu, t, T, t + 1, histB[t],
                                                  lastL ? nullptr : (ushort*)histB[t + 1],
                                                  lastL ? out : nullptr, N);
    }
}

// Round 4
// 413.052 us; speedup vs baseline: 1.4661x; 1.1642x over previous
//
#include <hip/hip_runtime.h>

#define DD 128   // feature dim
#define NP 256   // node partitions
#define EB 8192  // edges per binning block

typedef float4 f4;
typedef __attribute__((ext_vector_type(8))) short bf16x8;
typedef __attribute__((ext_vector_type(4))) float f32x4;

__device__ __forceinline__ short toBf(float f) {
    unsigned u = __float_as_uint(f);
    u += 0x7fff + ((u >> 16) & 1);   // RNE
    return (short)(u >> 16);
}
__device__ __forceinline__ float bf2f(unsigned short u) {
    return __uint_as_float(((unsigned)u) << 16);
}

// ---------------- setup: LDS-binned counting sort (no global atomics) ----------------

__global__ __launch_bounds__(1024) void kA(const int* __restrict__ ei, int E, int PSZ, int nbA,
                                           int* __restrict__ cntB_D, int* __restrict__ cntB_S) {
    __shared__ int hd[NP], hs[NP];
    int tid = threadIdx.x;
    if (tid < NP) { hd[tid] = 0; hs[tid] = 0; }
    __syncthreads();
    int base = blockIdx.x * EB;
    int lim = min(base + EB, E);
    for (int e = base + tid; e < lim; e += 1024) {
        int s = ei[e], d = ei[E + e];
        atomicAdd(&hs[s / PSZ], 1);
        atomicAdd(&hd[d / PSZ], 1);
    }
    __syncthreads();
    if (tid < NP) {
        cntB_D[tid * nbA + blockIdx.x] = hd[tid];
        cntB_S[tid * nbA + blockIdx.x] = hs[tid];
    }
}

// kB1: per-partition local exclusive scan of nbA per-block counters (one block per partition,
// D-role for b<NP, S-role for b>=NP); emits partition totals.
__global__ __launch_bounds__(512) void kB1(int* __restrict__ cntB_D, int* __restrict__ cntB_S,
                                           int nbA,
                                           int* __restrict__ partTotD, int* __restrict__ partTotS) {
    __shared__ int sh[512];
    int b = blockIdx.x, tid = threadIdx.x;
    int* cntB = (b < NP) ? cntB_D : cntB_S;
    int* partTot = (b < NP) ? partTotD : partTotS;
    int p = (b < NP) ? b : b - NP;
    int v = (tid < nbA) ? cntB[p * nbA + tid] : 0;
    sh[tid] = v; __syncthreads();
    for (int off = 1; off < 512; off <<= 1) {
        int add = (tid >= off) ? sh[tid - off] : 0;
        __syncthreads(); sh[tid] += add; __syncthreads();
    }
    if (tid < nbA) cntB[p * nbA + tid] = sh[tid] - v;   // local exclusive prefix
    if (tid == 511) partTot[p] = sh[511];
}

// kB2: single block; two independent 256-wide exclusive scans (D: lanes 0-255, S: 256-511).
__global__ __launch_bounds__(512) void kB2(const int* __restrict__ partTotD,
                                           const int* __restrict__ partTotS,
                                           int* __restrict__ partStartD,
                                           int* __restrict__ partStartS, int E) {
    __shared__ int sh[512];
    int tid = threadIdx.x;
    bool isD = tid < 256;
    int idx = isD ? tid : tid - 256;
    int v = isD ? partTotD[idx] : partTotS[idx];
    sh[tid] = v; __syncthreads();
    for (int off = 1; off < 256; off <<= 1) {
        int add = (idx >= off) ? sh[tid - off] : 0;   // idx>=off keeps halves independent
        __syncthreads(); sh[tid] += add; __syncthreads();
    }
    if (isD) partStartD[idx] = sh[tid] - v; else partStartS[idx] = sh[tid] - v;
    if (idx == 255) { if (isD) partStartD[NP] = E; else partStartS[NP] = E; }
}

__global__ __launch_bounds__(1024) void kC(const int* __restrict__ ei, const int* __restrict__ ea,
                                           int E, int N, int T, int PSZ, int nbA,
                                           const int* __restrict__ cntB_D, const int* __restrict__ cntB_S,
                                           const int* __restrict__ partStartD,
                                           const int* __restrict__ partStartS,
                                           int2* __restrict__ binD, int* __restrict__ binS) {
    __shared__ int pd[NP], ps[NP];
    int tid = threadIdx.x, b = blockIdx.x;
    if (tid < NP) {
        pd[tid] = cntB_D[tid * nbA + b] + partStartD[tid];
        ps[tid] = cntB_S[tid * nbA + b] + partStartS[tid];
    }
    __syncthreads();
    int base = b * EB;
    int lim = min(base + EB, E);
    for (int e = base + tid; e < lim; e += 1024) {
        int s = ei[e], d = ei[E + e], k = ea[e] - 1;
        int dp = d / PSZ, sp = s / PSZ;
        int posD = atomicAdd(&pd[dp], 1);
        binD[posD] = make_int2((d - dp * PSZ) * T + k, (k << 26) | (k * N + s));
        int posS = atomicAdd(&ps[sp], 1);
        binS[posS] = (s - sp * PSZ) * T + k;
    }
}

// fused kD (dst buckets -> rowptr/isdD2/ep) + kE (src degree -> isdS):
// blocks [0,NP) do D-role partition p=b; blocks [NP,2*NP) do S-role partition p=b-NP.
__global__ __launch_bounds__(512) void kDE(const int2* __restrict__ binD,
                                           const int* __restrict__ binS,
                                           const int* __restrict__ partStartD,
                                           const int* __restrict__ partStartS,
                                           int N, int T, int PSZ, int M, int E,
                                           int* __restrict__ rowptr, float* __restrict__ isdD2,
                                           int* __restrict__ ep, float* __restrict__ isdS) {
    __shared__ int cnt[4096];
    __shared__ int part[512];
    int b = blockIdx.x, tid = threadIdx.x;
    int nloc = PSZ * T;
    for (int i = tid; i < nloc; i += 512) cnt[i] = 0;
    __syncthreads();
    if (b < NP) {
        int p = b;
        int b0 = partStartD[p], b1 = partStartD[p + 1];
        for (int e = b0 + tid; e < b1; e += 512) atomicAdd(&cnt[binD[e].x], 1);
        __syncthreads();
        int CH = (nloc + 511) / 512;
        int c0 = tid * CH, c1 = min(c0 + CH, nloc);
        int s = 0;
        for (int i = c0; i < c1; i++) s += cnt[i];
        part[tid] = s; __syncthreads();
        for (int off = 1; off < 512; off <<= 1) {
            int add = (tid >= off) ? part[tid - off] : 0;
            __syncthreads(); part[tid] += add; __syncthreads();
        }
        int run = ((tid == 0) ? 0 : part[tid - 1]) + b0;
        int gb_base = p * PSZ * T;
        for (int i = c0; i < c1; i++) {
            int v = cnt[i];
            cnt[i] = run;
            int gb = gb_base + i;
            if (gb < M) {
                rowptr[gb] = run;
                isdD2[gb] = rsqrtf((float)max(v, 1));
            }
            run += v;
        }
        __syncthreads();
        for (int e = b0 + tid; e < b1; e += 512) {
            int2 v = binD[e];
            int pos = atomicAdd(&cnt[v.x], 1);
            ep[pos] = v.y;
        }
        if (p == 0 && tid == 0) rowptr[M] = E;
    } else {
        int p = b - NP;
        int b0 = partStartS[p], b1 = partStartS[p + 1];
        for (int e = b0 + tid; e < b1; e += 512) atomicAdd(&cnt[binS[e]], 1);
        __syncthreads();
        int s0 = p * PSZ;
        for (int i = tid; i < nloc; i += 512) {
            int sl = i / T, k = i - sl * T;
            int snode = s0 + sl;
            if (snode < N) isdS[k * N + snode] = rsqrtf((float)max(cnt[i], 1));
        }
    }
}

__global__ void k_prepW(const float* __restrict__ W, ushort* __restrict__ WT, int tot) {
    int i = blockIdx.x * blockDim.x + threadIdx.x;
    if (i >= tot) return;
    int k = i >> 14, rem = i & 16383, j = rem >> 7, d = rem & 127;
    WT[i] = (ushort)toBf(W[(size_t)k * 16384 + (size_t)d * DD + j]);   // WT[k][j][d] = W[k][d][j]
}

__global__ void k_cvt(const float* __restrict__ x, ushort* __restrict__ xb, int n8) {
    int i = blockIdx.x * blockDim.x + threadIdx.x;
    if (i >= n8) return;
    const f4* q = (const f4*)(x + (size_t)i * 8);
    f4 lo = q[0], hi = q[1];
    bf16x8 r;
    r[0] = toBf(lo.x); r[1] = toBf(lo.y); r[2] = toBf(lo.z); r[3] = toBf(lo.w);
    r[4] = toBf(hi.x); r[5] = toBf(hi.y); r[6] = toBf(hi.z); r[7] = toBf(hi.w);
    *(bf16x8*)(xb + (size_t)i * 8) = r;
}

// ------- batched GEMM: H'_k0[N,128](bf16) = diag(isk) * (A_k0 @ W_k0), MFMA -------
// W staged in LDS (32 KB) with 16B-granule XOR swizzle; 256 rows/block, 64 rows/wave.

struct APtrs { const ushort* a0; const ushort* a1; const ushort* a2; const ushort* a3; };

__global__ __launch_bounds__(256) void k_gemm_batch(APtrs ap,
                                                    const ushort* __restrict__ WTb,
                                                    const float* __restrict__ iskb,
                                                    ushort* __restrict__ Hb, int N) {
    __shared__ ushort lW[128 * 128];   // 32 KB
    int k0 = blockIdx.y;
    const ushort* A = (k0 == 0) ? ap.a0 : (k0 == 1) ? ap.a1 : (k0 == 2) ? ap.a2 : ap.a3;
    const ushort* WT = WTb + (size_t)k0 * DD * DD;
    const float* isk = iskb + (size_t)k0 * N;
    ushort* H = Hb + (size_t)k0 * N * DD;

    int tid = threadIdx.x;
    // stage W: 2048 16B granules, swizzled slot = slot ^ (row&7)
#pragma unroll
    for (int i = 0; i < 8; i++) {
        int g = tid + i * 256;
        int row = g >> 4, slot = g & 15;
        bf16x8 v = *(const bf16x8*)(WT + row * DD + slot * 8);
        *(bf16x8*)(lW + row * DD + (slot ^ (row & 7)) * 8) = v;
    }
    __syncthreads();

    int wave = tid >> 6;
    int lane = tid & 63;
    int rlo = lane & 15;       // A row within strip / C col within 16
    int khi = lane >> 4;       // 0..3
    int r0 = blockIdx.x * 256 + wave * 64;

    f32x4 acc[4][8];
#pragma unroll
    for (int s = 0; s < 4; s++)
#pragma unroll
        for (int j = 0; j < 8; j++) acc[s][j] = (f32x4){0.f, 0.f, 0.f, 0.f};

    int ca[4];
#pragma unroll
    for (int s = 0; s < 4; s++) {
        int r = r0 + s * 16 + rlo;
        ca[s] = r < N ? r : N - 1;
    }

#pragma unroll
    for (int kk = 0; kk < 4; kk++) {
        int d0 = kk * 32 + khi * 8;
        bf16x8 a[4];
#pragma unroll
        for (int s = 0; s < 4; s++)
            a[s] = *(const bf16x8*)(A + (size_t)ca[s] * DD + d0);
        int q = kk * 4 + khi;   // 16B slot index along d
#pragma unroll
        for (int cg = 0; cg < 8; cg++) {
            int row = cg * 16 + rlo;
            bf16x8 b = *(const bf16x8*)(lW + row * DD + (q ^ (rlo & 7)) * 8);
#pragma unroll
            for (int s = 0; s < 4; s++)
                acc[s][cg] = __builtin_amdgcn_mfma_f32_16x16x32_bf16(a[s], b, acc[s][cg], 0, 0, 0);
        }
    }

#pragma unroll
    for (int s = 0; s < 4; s++) {
#pragma unroll
        for (int r = 0; r < 4; r++) {
            int row = r0 + s * 16 + khi * 4 + r;
            if (row < N) {
                float sc = isk[row];
#pragma unroll
                for (int cg = 0; cg < 8; cg++)
                    H[(size_t)row * DD + cg * 16 + rlo] = (ushort)toBf(sc * acc[s][cg][r]);
            }
        }
    }
}

// ------- fused per-layer: gather-sum over contiguous segment; out = l2norm(hist + relu(acc)) -------

__device__ __forceinline__ float selw(float w0, float w1, float w2, float w3, int k) {
    float a = (k & 1) ? w1 : w0;
    float b = (k & 1) ? w3 : w2;
    return (k & 2) ? b : a;
}

__global__ __launch_bounds__(256) void k_agg_fin(
        const ushort* __restrict__ H,        // T*N rows of 128 bf16, row idx = k*N+src
        const int* __restrict__ ep,          // packed payloads, (dst,k)-bucket order
        const int* __restrict__ rp,          // M+1 rowptr, bucket = d*T+k
        const float* __restrict__ isdD2,     // M, d*T+k
        const float* __restrict__ nu, int t, int T, int nk,
        const ushort* __restrict__ hp,       // residual input (bf16)
        ushort* __restrict__ hnB,            // bf16 hist output (t < T-1)
        float* __restrict__ outF,            // f32 output (t == T-1), else null
        int N) {
    int node = (blockIdx.x * blockDim.x + threadIdx.x) >> 5;
    if (node >= N) return;
    int lane = threadIdx.x & 31;
    int rbase = node * T;
    int b0 = rp[rbase], b1 = rp[rbase + nk];

    float w0 = nu[t] * isdD2[rbase];
    float w1 = (1 < nk) ? nu[T + t]     * isdD2[rbase + 1] : 0.f;
    float w2 = (2 < nk) ? nu[2 * T + t] * isdD2[rbase + 2] : 0.f;
    float w3 = (3 < nk) ? nu[3 * T + t] * isdD2[rbase + 3] : 0.f;

    const char* Hc = (const char*)H;
    unsigned lb = (unsigned)lane << 3;   // byte offset of this lane's 8B within a 256B row

    float sx = 0.f, sy = 0.f, sz = 0.f, sw = 0.f;
    int e = b0;

// decode payload -> 32-bit byte offset + coefficient
#define DEC(P, O, C) \
    O = ((((unsigned)(P)) & 0x3FFFFFFu) << 8) | lb; \
    C = selw(w0, w1, w2, w3, (P) >> 26);

// accumulate one gathered uint2 (4 bf16) with coefficient C
#define ACC(G, C) { \
    float f0 = __uint_as_float((G).x << 16); \
    float f1 = __uint_as_float((G).x & 0xffff0000u); \
    float f2 = __uint_as_float((G).y << 16); \
    float f3 = __uint_as_float((G).y & 0xffff0000u); \
    sx = fmaf((C), f0, sx); sy = fmaf((C), f1, sy); \
    sz = fmaf((C), f2, sz); sw = fmaf((C), f3, sw); }

    // 8-deep main loop: 8 payload loads, then 8 gathers in flight (2 KB/group)
    for (; e + 7 < b1; e += 8) {
        int p0 = ep[e],     p1 = ep[e + 1], p2 = ep[e + 2], p3 = ep[e + 3];
        int p4 = ep[e + 4], p5 = ep[e + 5], p6 = ep[e + 6], p7 = ep[e + 7];
        unsigned o0, o1, o2, o3, o4, o5, o6, o7;
        float c0, c1, c2, c3, c4, c5, c6, c7;
        DEC(p0, o0, c0) DEC(p1, o1, c1) DEC(p2, o2, c2) DEC(p3, o3, c3)
        DEC(p4, o4, c4) DEC(p5, o5, c5) DEC(p6, o6, c6) DEC(p7, o7, c7)
        uint2 g0 = *(const uint2*)(Hc + o0);
        uint2 g1 = *(const uint2*)(Hc + o1);
        uint2 g2 = *(const uint2*)(Hc + o2);
        uint2 g3 = *(const uint2*)(Hc + o3);
        uint2 g4 = *(const uint2*)(Hc + o4);
        uint2 g5 = *(const uint2*)(Hc + o5);
        uint2 g6 = *(const uint2*)(Hc + o6);
        uint2 g7 = *(const uint2*)(Hc + o7);
        ACC(g0, c0) ACC(g1, c1) ACC(g2, c2) ACC(g3, c3)
        ACC(g4, c4) ACC(g5, c5) ACC(g6, c6) ACC(g7, c7)
    }
    // 4-deep tier
    if (e + 3 < b1) {
        int p0 = ep[e], p1 = ep[e + 1], p2 = ep[e + 2], p3 = ep[e + 3];
        unsigned o0, o1, o2, o3;
        float c0, c1, c2, c3;
        DEC(p0, o0, c0) DEC(p1, o1, c1) DEC(p2, o2, c2) DEC(p3, o3, c3)
        uint2 g0 = *(const uint2*)(Hc + o0);
        uint2 g1 = *(const uint2*)(Hc + o1);
        uint2 g2 = *(const uint2*)(Hc + o2);
        uint2 g3 = *(const uint2*)(Hc + o3);
        ACC(g0, c0) ACC(g1, c1) ACC(g2, c2) ACC(g3, c3)
        e += 4;
    }
    // scalar tail
    for (; e < b1; e++) {
        int p0 = ep[e];
        unsigned o0; float c0;
        DEC(p0, o0, c0)
        uint2 g0 = *(const uint2*)(Hc + o0);
        ACC(g0, c0)
    }
#undef DEC
#undef ACC

    unsigned nodeOff = ((unsigned)node << 8) | lb;
    uint2 hv = *(const uint2*)((const char*)hp + nodeOff);
    float vx = __uint_as_float(hv.x << 16)         + fmaxf(sx, 0.f);
    float vy = __uint_as_float(hv.x & 0xffff0000u) + fmaxf(sy, 0.f);
    float vz = __uint_as_float(hv.y << 16)         + fmaxf(sz, 0.f);
    float vw = __uint_as_float(hv.y & 0xffff0000u) + fmaxf(sw, 0.f);
    float ss = vx * vx + vy * vy + vz * vz + vw * vw;
#pragma unroll
    for (int off = 16; off; off >>= 1) ss += __shfl_xor(ss, off, 32);
    float inv = 1.f / fmaxf(sqrtf(ss), 1e-12f);
    vx *= inv; vy *= inv; vz *= inv; vw *= inv;
    if (outF) {
        f4 o; o.x = vx; o.y = vy; o.z = vz; o.w = vw;
        *(f4*)((char*)outF + (((size_t)node << 9) | ((size_t)lane << 4))) = o;
    } else {
        uint lo = ((unsigned)(unsigned short)toBf(vx)) | (((unsigned)(unsigned short)toBf(vy)) << 16);
        uint hi = ((unsigned)(unsigned short)toBf(vz)) | (((unsigned)(unsigned short)toBf(vw)) << 16);
        uint2 ob; ob.x = lo; ob.y = hi;
        *(uint2*)((char*)hnB + nodeOff) = ob;
    }
}

// ---------------- driver ----------------

extern "C" void kernel_launch(void* const* d_in, const int* in_sizes, int n_in,
                              void* d_out, int out_size, void* d_ws, size_t ws_size,
                              hipStream_t stream) {
    const float* x  = (const float*)d_in[0];
    const int*   ei = (const int*)d_in[1];
    const int*   ea = (const int*)d_in[2];
    const float* W  = (const float*)d_in[3];
    const float* nu = (const float*)d_in[4];
    float* out = (float*)d_out;

    int N = in_sizes[0] / DD;
    int E = in_sizes[1] / 2;
    int T = in_sizes[3] / (DD * DD);
    int M = T * N;
    size_t ND = (size_t)N * DD;

    int PSZ = (N + NP - 1) / NP;          // nodes per partition
    if (PSZ * T > 4096) return;           // LDS counter budget guard
    int nbA = (E + EB - 1) / EB;          // binning blocks
    if (nbA > 512) return;                // kB1 single-pass scan guard

    // workspace layout
    float*  isdS  = (float*)d_ws;            // M f32 (k-major, rsqrt deg_src)
    float*  isdD2 = isdS + M;                // M f32 (dst-major d*T+k, rsqrt deg_dst)
    ushort* xb    = (ushort*)(isdD2 + M);    // ND bf16
    ushort* h1b   = xb + ND;                 // ND bf16
    ushort* h2b   = h1b + ND;                // ND bf16
    ushort* h3b   = h2b + ND;                // ND bf16
    ushort* Hb    = h3b + ND;                // T*ND bf16 (pre-scaled H'_k)
    ushort* WT    = Hb + (size_t)T * ND;     // T*128*128 bf16
    int* rowptr   = (int*)(WT + (size_t)T * DD * DD);  // M+1
    int* ep       = rowptr + M + 1;          // E
    // setup scratch aliases Hb (setup strictly precedes GEMM writes)
    int2* binD       = (int2*)Hb;                        // E int2
    int*  binS       = (int*)(binD + E);                 // E
    int*  cntB_D     = binS + E;                         // NP*nbA
    int*  cntB_S     = cntB_D + NP * nbA;                // NP*nbA
    int*  partStartD = cntB_S + NP * nbA;                // NP+1
    int*  partStartS = partStartD + NP + 1;              // NP+1
    int*  partTotD   = partStartS + NP + 1;              // NP
    int*  partTotS   = partTotD + NP;                    // NP

    size_t req = sizeof(float) * 2 * (size_t)M
               + sizeof(ushort) * ((size_t)(4 + T) * ND + (size_t)T * DD * DD)
               + sizeof(int) * ((size_t)M + 1 + (size_t)E + 64);
    if (ws_size < req) return;
    size_t scratch = sizeof(int) * (3 * (size_t)E + 2 * (size_t)NP * nbA + 4 * (NP + 1));
    if (scratch > sizeof(ushort) * (size_t)T * ND) return;

    kA<<<nbA, 1024, 0, stream>>>(ei, E, PSZ, nbA, cntB_D, cntB_S);
    kB1<<<2 * NP, 512, 0, stream>>>(cntB_D, cntB_S, nbA, partTotD, partTotS);
    kB2<<<1, 512, 0, stream>>>(partTotD, partTotS, partStartD, partStartS, E);
    kC<<<nbA, 1024, 0, stream>>>(ei, ea, E, N, T, PSZ, nbA, cntB_D, cntB_S,
                                 partStartD, partStartS, binD, binS);
    kDE<<<2 * NP, 512, 0, stream>>>(binD, binS, partStartD, partStartS,
                                    N, T, PSZ, M, E, rowptr, isdD2, ep, isdS);
    k_prepW<<<(T * DD * DD + 255) / 256, 256, 0, stream>>>(W, WT, T * DD * DD);
    k_cvt<<<((int)(ND / 8) + 255) / 256, 256, 0, stream>>>(x, xb, (int)(ND / 8));

    const ushort* histB[4] = {xb, h1b, h2b, h3b};

    int nodeBlocks = ((size_t)N * 32 + 255) / 256;
    int gemmBlocks = (N + 255) / 256;

    for (int t = 0; t < T; t++) {
        APtrs ap;
        ap.a0 = histB[t];
        ap.a1 = (t >= 1) ? histB[t - 1] : histB[0];
        ap.a2 = (t >= 2) ? histB[t - 2] : histB[0];
        ap.a3 = (t >= 3) ? histB[t - 3] : histB[0];
        dim3 grid(gemmBlocks, t + 1);
        k_gemm_batch<<<grid, 256, 0, stream>>>(ap, WT, isdS, Hb, N);

        bool lastL = (t == T - 1);
        k_agg_fin<<<nodeBlocks, 256, 0, stream>>>(Hb, ep, rowptr, isdD2,
                                                  nu, t, T, t + 1, histB[t],
                                                  lastL ? nullptr : (ushort*)histB[t + 1],
                                                  lastL ? out : nullptr, N);
    }
}

// Round 5
// 408.705 us; speedup vs baseline: 1.4817x; 1.0106x over previous
//
#include <hip/hip_runtime.h>

#define DD 128   // feature dim
#define NP 256   // node partitions
#define EB 4096  // edges per binning block

typedef float4 f4;
typedef __attribute__((ext_vector_type(8))) short bf16x8;
typedef __attribute__((ext_vector_type(4))) float f32x4;

__device__ __forceinline__ short toBf(float f) {
    unsigned u = __float_as_uint(f);
    u += 0x7fff + ((u >> 16) & 1);   // RNE
    return (short)(u >> 16);
}
__device__ __forceinline__ float bf2f(unsigned short u) {
    return __uint_as_float(((unsigned)u) << 16);
}

// ---------------- setup: LDS-binned counting sort (no global atomics) ----------------
// payload packing (32-bit): [31:21] local bucket (dloc*T+k, <2048) | [20:19] k | [18:0] row = k*N+s

// fused: blocks [0,nbA) = histogram role; [nbA,nbA+nPW) = prepW; rest = cvt
__global__ __launch_bounds__(1024) void kAF(const int* __restrict__ ei, int E, int PSZ, int nbA,
                                            int* __restrict__ cntB_D, int* __restrict__ cntB_S,
                                            const float* __restrict__ W, ushort* __restrict__ WT,
                                            int totW, int nPW,
                                            const float* __restrict__ x, ushort* __restrict__ xb,
                                            int n8) {
    __shared__ int hd[NP], hs[NP];
    int tid = threadIdx.x, b = blockIdx.x;
    if (b < nbA) {
        if (tid < NP) { hd[tid] = 0; hs[tid] = 0; }
        __syncthreads();
        int base = b * EB;
        int lim = min(base + EB, E);
        for (int e = base + tid; e < lim; e += 1024) {
            int s = ei[e], d = ei[E + e];
            atomicAdd(&hs[s / PSZ], 1);
            atomicAdd(&hd[d / PSZ], 1);
        }
        __syncthreads();
        if (tid < NP) {
            cntB_D[tid * nbA + b] = hd[tid];
            cntB_S[tid * nbA + b] = hs[tid];
        }
    } else if (b < nbA + nPW) {
        int i = (b - nbA) * 1024 + tid;
        if (i < totW) {
            int k = i >> 14, rem = i & 16383, j = rem >> 7, d = rem & 127;
            WT[i] = (ushort)toBf(W[(size_t)k * 16384 + (size_t)d * DD + j]);  // WT[k][j][d] = W[k][d][j]
        }
    } else {
        int i = (b - nbA - nPW) * 1024 + tid;
        if (i < n8) {
            const f4* q = (const f4*)(x + (size_t)i * 8);
            f4 lo = q[0], hi = q[1];
            bf16x8 r;
            r[0] = toBf(lo.x); r[1] = toBf(lo.y); r[2] = toBf(lo.z); r[3] = toBf(lo.w);
            r[4] = toBf(hi.x); r[5] = toBf(hi.y); r[6] = toBf(hi.z); r[7] = toBf(hi.w);
            *(bf16x8*)(xb + (size_t)i * 8) = r;
        }
    }
}

// kB1: per-partition local exclusive scan of nbA per-block counters (one block per partition,
// D-role for b<NP, S-role for b>=NP); emits partition totals.
__global__ __launch_bounds__(512) void kB1(int* __restrict__ cntB_D, int* __restrict__ cntB_S,
                                           int nbA,
                                           int* __restrict__ partTotD, int* __restrict__ partTotS) {
    __shared__ int sh[512];
    int b = blockIdx.x, tid = threadIdx.x;
    int* cntB = (b < NP) ? cntB_D : cntB_S;
    int* partTot = (b < NP) ? partTotD : partTotS;
    int p = (b < NP) ? b : b - NP;
    int v = (tid < nbA) ? cntB[p * nbA + tid] : 0;
    sh[tid] = v; __syncthreads();
    for (int off = 1; off < 512; off <<= 1) {
        int add = (tid >= off) ? sh[tid - off] : 0;
        __syncthreads(); sh[tid] += add; __syncthreads();
    }
    if (tid < nbA) cntB[p * nbA + tid] = sh[tid] - v;   // local exclusive prefix
    if (tid == 511) partTot[p] = sh[511];
}

__global__ __launch_bounds__(1024) void kC(const int* __restrict__ ei, const int* __restrict__ ea,
                                           int E, int N, int T, int PSZ, int nbA,
                                           const int* __restrict__ cntB_D, const int* __restrict__ cntB_S,
                                           const int* __restrict__ partTotD,
                                           const int* __restrict__ partTotS,
                                           int* __restrict__ binD, ushort* __restrict__ binS) {
    __shared__ int pd[NP], ps[NP];
    __shared__ int sc[512];
    int tid = threadIdx.x, b = blockIdx.x;
    // segmented inclusive scan: lanes 0-255 = partTotD, 256-511 = partTotS
    if (tid < 512) sc[tid] = (tid < 256) ? partTotD[tid] : partTotS[tid - 256];
    __syncthreads();
    for (int off = 1; off < 256; off <<= 1) {
        int add = 0;
        if (tid < 512 && (tid & 255) >= off) add = sc[tid - off];
        __syncthreads();
        if (tid < 512) sc[tid] += add;
        __syncthreads();
    }
    if (tid < NP) {
        pd[tid] = cntB_D[tid * nbA + b] + (sc[tid] - partTotD[tid]);
        ps[tid] = cntB_S[tid * nbA + b] + (sc[tid + 256] - partTotS[tid]);
    }
    __syncthreads();
    int base = b * EB;
    int lim = min(base + EB, E);
    for (int e = base + tid; e < lim; e += 1024) {
        int s = ei[e], d = ei[E + e], k = ea[e] - 1;
        int dp = d / PSZ, sp = s / PSZ;
        int loc = (d - dp * PSZ) * T + k;
        int posD = atomicAdd(&pd[dp], 1);
        binD[posD] = (loc << 21) | (k << 19) | (k * N + s);
        int posS = atomicAdd(&ps[sp], 1);
        binS[posS] = (ushort)((s - sp * PSZ) * T + k);
    }
}

// fused kD (dst buckets -> rowptr/isdD2/ep) + kE (src degree -> isdS):
// blocks [0,NP) do D-role partition p=b; blocks [NP,2*NP) do S-role partition p=b-NP.
__global__ __launch_bounds__(512) void kDE(const int* __restrict__ binD,
                                           const ushort* __restrict__ binS,
                                           const int* __restrict__ partTotD,
                                           const int* __restrict__ partTotS,
                                           int N, int T, int PSZ, int M, int E,
                                           int* __restrict__ rowptr, float* __restrict__ isdD2,
                                           int* __restrict__ ep, float* __restrict__ isdS) {
    __shared__ int cnt[4096];
    __shared__ int part[512];
    __shared__ int sc[256];
    int b = blockIdx.x, tid = threadIdx.x;
    bool isD = b < NP;
    int p = isD ? b : b - NP;
    const int* pt = isD ? partTotD : partTotS;
    if (tid < 256) sc[tid] = pt[tid];
    __syncthreads();
    for (int off = 1; off < 256; off <<= 1) {
        int add = (tid < 256 && tid >= off) ? sc[tid - off] : 0;
        __syncthreads();
        if (tid < 256) sc[tid] += add;
        __syncthreads();
    }
    int b1 = sc[p];
    int b0 = b1 - pt[p];
    __syncthreads();
    int nloc = PSZ * T;
    for (int i = tid; i < nloc; i += 512) cnt[i] = 0;
    __syncthreads();
    if (isD) {
        for (int e = b0 + tid; e < b1; e += 512)
            atomicAdd(&cnt[((unsigned)binD[e]) >> 21], 1);
        __syncthreads();
        int CH = (nloc + 511) / 512;
        int c0 = tid * CH, c1 = min(c0 + CH, nloc);
        int s = 0;
        for (int i = c0; i < c1; i++) s += cnt[i];
        part[tid] = s; __syncthreads();
        for (int off = 1; off < 512; off <<= 1) {
            int add = (tid >= off) ? part[tid - off] : 0;
            __syncthreads(); part[tid] += add; __syncthreads();
        }
        int run = ((tid == 0) ? 0 : part[tid - 1]) + b0;
        int gb_base = p * PSZ * T;
        for (int i = c0; i < c1; i++) {
            int v = cnt[i];
            cnt[i] = run;
            int gb = gb_base + i;
            if (gb < M) {
                rowptr[gb] = run;
                isdD2[gb] = rsqrtf((float)max(v, 1));
            }
            run += v;
        }
        __syncthreads();
        for (int e = b0 + tid; e < b1; e += 512) {
            int v = binD[e];
            int pos = atomicAdd(&cnt[((unsigned)v) >> 21], 1);
            ep[pos] = v & 0x1FFFFF;
        }
        if (p == 0 && tid == 0) rowptr[M] = E;
    } else {
        for (int e = b0 + tid; e < b1; e += 512)
            atomicAdd(&cnt[(int)binS[e]], 1);
        __syncthreads();
        int s0 = p * PSZ;
        for (int i = tid; i < nloc; i += 512) {
            int sl = i / T, k = i - sl * T;
            int snode = s0 + sl;
            if (snode < N) isdS[k * N + snode] = rsqrtf((float)max(cnt[i], 1));
        }
    }
}

// ------- batched GEMM: H'_k0[N,128](bf16) = diag(isk) * (A_k0 @ W_k0), MFMA -------
// W staged in LDS (32 KB) with 16B-granule XOR swizzle; 256 rows/block, 64 rows/wave.

struct APtrs { const ushort* a0; const ushort* a1; const ushort* a2; const ushort* a3; };

__global__ __launch_bounds__(256) void k_gemm_batch(APtrs ap,
                                                    const ushort* __restrict__ WTb,
                                                    const float* __restrict__ iskb,
                                                    ushort* __restrict__ Hb, int N) {
    __shared__ ushort lW[128 * 128];   // 32 KB
    int k0 = blockIdx.y;
    const ushort* A = (k0 == 0) ? ap.a0 : (k0 == 1) ? ap.a1 : (k0 == 2) ? ap.a2 : ap.a3;
    const ushort* WT = WTb + (size_t)k0 * DD * DD;
    const float* isk = iskb + (size_t)k0 * N;
    ushort* H = Hb + (size_t)k0 * N * DD;

    int tid = threadIdx.x;
    // stage W: 2048 16B granules, swizzled slot = slot ^ (row&7)
#pragma unroll
    for (int i = 0; i < 8; i++) {
        int g = tid + i * 256;
        int row = g >> 4, slot = g & 15;
        bf16x8 v = *(const bf16x8*)(WT + row * DD + slot * 8);
        *(bf16x8*)(lW + row * DD + (slot ^ (row & 7)) * 8) = v;
    }
    __syncthreads();

    int wave = tid >> 6;
    int lane = tid & 63;
    int rlo = lane & 15;       // A row within strip / C col within 16
    int khi = lane >> 4;       // 0..3
    int r0 = blockIdx.x * 256 + wave * 64;

    f32x4 acc[4][8];
#pragma unroll
    for (int s = 0; s < 4; s++)
#pragma unroll
        for (int j = 0; j < 8; j++) acc[s][j] = (f32x4){0.f, 0.f, 0.f, 0.f};

    int ca[4];
#pragma unroll
    for (int s = 0; s < 4; s++) {
        int r = r0 + s * 16 + rlo;
        ca[s] = r < N ? r : N - 1;
    }

#pragma unroll
    for (int kk = 0; kk < 4; kk++) {
        int d0 = kk * 32 + khi * 8;
        bf16x8 a[4];
#pragma unroll
        for (int s = 0; s < 4; s++)
            a[s] = *(const bf16x8*)(A + (size_t)ca[s] * DD + d0);
        int q = kk * 4 + khi;   // 16B slot index along d
#pragma unroll
        for (int cg = 0; cg < 8; cg++) {
            int row = cg * 16 + rlo;
            bf16x8 b = *(const bf16x8*)(lW + row * DD + (q ^ (rlo & 7)) * 8);
#pragma unroll
            for (int s = 0; s < 4; s++)
                acc[s][cg] = __builtin_amdgcn_mfma_f32_16x16x32_bf16(a[s], b, acc[s][cg], 0, 0, 0);
        }
    }

#pragma unroll
    for (int s = 0; s < 4; s++) {
#pragma unroll
        for (int r = 0; r < 4; r++) {
            int row = r0 + s * 16 + khi * 4 + r;
            if (row < N) {
                float sc = isk[row];
#pragma unroll
                for (int cg = 0; cg < 8; cg++)
                    H[(size_t)row * DD + cg * 16 + rlo] = (ushort)toBf(sc * acc[s][cg][r]);
            }
        }
    }
}

// ------- fused per-layer: gather-sum over contiguous segment; out = l2norm(hist + relu(acc)) -------

__device__ __forceinline__ float selw(float w0, float w1, float w2, float w3, int k) {
    float a = (k & 1) ? w1 : w0;
    float b = (k & 1) ? w3 : w2;
    return (k & 2) ? b : a;
}

__global__ __launch_bounds__(256) void k_agg_fin(
        const ushort* __restrict__ H,        // T*N rows of 128 bf16, row idx = k*N+src
        const int* __restrict__ ep,          // packed payloads (k<<19|row), (dst,k)-bucket order
        const int* __restrict__ rp,          // M+1 rowptr, bucket = d*T+k
        const float* __restrict__ isdD2,     // M, d*T+k
        const float* __restrict__ nu, int t, int T, int nk,
        const ushort* __restrict__ hp,       // residual input (bf16)
        ushort* __restrict__ hnB,            // bf16 hist output (t < T-1)
        float* __restrict__ outF,            // f32 output (t == T-1), else null
        int N) {
    int node = (blockIdx.x * blockDim.x + threadIdx.x) >> 5;
    if (node >= N) return;
    int lane = threadIdx.x & 31;
    int rbase = node * T;
    int b0 = rp[rbase], b1 = rp[rbase + nk];

    float w0 = nu[t] * isdD2[rbase];
    float w1 = (1 < nk) ? nu[T + t]     * isdD2[rbase + 1] : 0.f;
    float w2 = (2 < nk) ? nu[2 * T + t] * isdD2[rbase + 2] : 0.f;
    float w3 = (3 < nk) ? nu[3 * T + t] * isdD2[rbase + 3] : 0.f;

    const char* Hc = (const char*)H;
    unsigned lb = (unsigned)lane << 3;   // byte offset of this lane's 8B within a 256B row

    float sx = 0.f, sy = 0.f, sz = 0.f, sw = 0.f;
    int e = b0;

// decode payload -> 32-bit byte offset + coefficient
#define DEC(P, O, C) \
    O = ((((unsigned)(P)) & 0x7FFFFu) << 8) | lb; \
    C = selw(w0, w1, w2, w3, (P) >> 19);

// accumulate one gathered uint2 (4 bf16) with coefficient C
#define ACC(G, C) { \
    float f0 = __uint_as_float((G).x << 16); \
    float f1 = __uint_as_float((G).x & 0xffff0000u); \
    float f2 = __uint_as_float((G).y << 16); \
    float f3 = __uint_as_float((G).y & 0xffff0000u); \
    sx = fmaf((C), f0, sx); sy = fmaf((C), f1, sy); \
    sz = fmaf((C), f2, sz); sw = fmaf((C), f3, sw); }

    // 8-deep main loop: 8 payload loads, then 8 gathers in flight (2 KB/group)
    for (; e + 7 < b1; e += 8) {
        int p0 = ep[e],     p1 = ep[e + 1], p2 = ep[e + 2], p3 = ep[e + 3];
        int p4 = ep[e + 4], p5 = ep[e + 5], p6 = ep[e + 6], p7 = ep[e + 7];
        unsigned o0, o1, o2, o3, o4, o5, o6, o7;
        float c0, c1, c2, c3, c4, c5, c6, c7;
        DEC(p0, o0, c0) DEC(p1, o1, c1) DEC(p2, o2, c2) DEC(p3, o3, c3)
        DEC(p4, o4, c4) DEC(p5, o5, c5) DEC(p6, o6, c6) DEC(p7, o7, c7)
        uint2 g0 = *(const uint2*)(Hc + o0);
        uint2 g1 = *(const uint2*)(Hc + o1);
        uint2 g2 = *(const uint2*)(Hc + o2);
        uint2 g3 = *(const uint2*)(Hc + o3);
        uint2 g4 = *(const uint2*)(Hc + o4);
        uint2 g5 = *(const uint2*)(Hc + o5);
        uint2 g6 = *(const uint2*)(Hc + o6);
        uint2 g7 = *(const uint2*)(Hc + o7);
        ACC(g0, c0) ACC(g1, c1) ACC(g2, c2) ACC(g3, c3)
        ACC(g4, c4) ACC(g5, c5) ACC(g6, c6) ACC(g7, c7)
    }
    // 4-deep tier
    if (e + 3 < b1) {
        int p0 = ep[e], p1 = ep[e + 1], p2 = ep[e + 2], p3 = ep[e + 3];
        unsigned o0, o1, o2, o3;
        float c0, c1, c2, c3;
        DEC(p0, o0, c0) DEC(p1, o1, c1) DEC(p2, o2, c2) DEC(p3, o3, c3)
        uint2 g0 = *(const uint2*)(Hc + o0);
        uint2 g1 = *(const uint2*)(Hc + o1);
        uint2 g2 = *(const uint2*)(Hc + o2);
        uint2 g3 = *(const uint2*)(Hc + o3);
        ACC(g0, c0) ACC(g1, c1) ACC(g2, c2) ACC(g3, c3)
        e += 4;
    }
    // scalar tail
    for (; e < b1; e++) {
        int p0 = ep[e];
        unsigned o0; float c0;
        DEC(p0, o0, c0)
        uint2 g0 = *(const uint2*)(Hc + o0);
        ACC(g0, c0)
    }
#undef DEC
#undef ACC

    unsigned nodeOff = ((unsigned)node << 8) | lb;
    uint2 hv = *(const uint2*)((const char*)hp + nodeOff);
    float vx = __uint_as_float(hv.x << 16)         + fmaxf(sx, 0.f);
    float vy = __uint_as_float(hv.x & 0xffff0000u) + fmaxf(sy, 0.f);
    float vz = __uint_as_float(hv.y << 16)         + fmaxf(sz, 0.f);
    float vw = __uint_as_float(hv.y & 0xffff0000u) + fmaxf(sw, 0.f);
    float ss = vx * vx + vy * vy + vz * vz + vw * vw;
#pragma unroll
    for (int off = 16; off; off >>= 1) ss += __shfl_xor(ss, off, 32);
    float inv = 1.f / fmaxf(sqrtf(ss), 1e-12f);
    vx *= inv; vy *= inv; vz *= inv; vw *= inv;
    if (outF) {
        f4 o; o.x = vx; o.y = vy; o.z = vz; o.w = vw;
        *(f4*)((char*)outF + (((size_t)node << 9) | ((size_t)lane << 4))) = o;
    } else {
        uint lo = ((unsigned)(unsigned short)toBf(vx)) | (((unsigned)(unsigned short)toBf(vy)) << 16);
        uint hi = ((unsigned)(unsigned short)toBf(vz)) | (((unsigned)(unsigned short)toBf(vw)) << 16);
        uint2 ob; ob.x = lo; ob.y = hi;
        *(uint2*)((char*)hnB + nodeOff) = ob;
    }
}

// ---------------- driver ----------------

extern "C" void kernel_launch(void* const* d_in, const int* in_sizes, int n_in,
                              void* d_out, int out_size, void* d_ws, size_t ws_size,
                              hipStream_t stream) {
    const float* x  = (const float*)d_in[0];
    const int*   ei = (const int*)d_in[1];
    const int*   ea = (const int*)d_in[2];
    const float* W  = (const float*)d_in[3];
    const float* nu = (const float*)d_in[4];
    float* out = (float*)d_out;

    int N = in_sizes[0] / DD;
    int E = in_sizes[1] / 2;
    int T = in_sizes[3] / (DD * DD);
    int M = T * N;
    size_t ND = (size_t)N * DD;

    int PSZ = (N + NP - 1) / NP;          // nodes per partition
    if (PSZ * T > 2048) return;           // payload loc-bits + LDS counter budget guard
    if ((long)T * N > (1L << 19)) return; // payload row-bits guard
    int nbA = (E + EB - 1) / EB;          // binning blocks
    if (nbA > 512) return;                // kB1 single-pass scan guard

    // workspace layout
    float*  isdS  = (float*)d_ws;            // M f32 (k-major, rsqrt deg_src)
    float*  isdD2 = isdS + M;                // M f32 (dst-major d*T+k, rsqrt deg_dst)
    ushort* xb    = (ushort*)(isdD2 + M);    // ND bf16
    ushort* h1b   = xb + ND;                 // ND bf16
    ushort* h2b   = h1b + ND;                // ND bf16
    ushort* h3b   = h2b + ND;                // ND bf16
    ushort* Hb    = h3b + ND;                // T*ND bf16 (pre-scaled H'_k)
    ushort* WT    = Hb + (size_t)T * ND;     // T*128*128 bf16
    int* rowptr   = (int*)(WT + (size_t)T * DD * DD);  // M+1
    int* ep       = rowptr + M + 1;          // E
    // setup scratch aliases Hb (setup strictly precedes GEMM writes)
    int*    binD     = (int*)Hb;                         // E
    ushort* binS     = (ushort*)(binD + E);              // E
    int*    cntB_D   = (int*)(binS + (((size_t)E + 1) & ~(size_t)1));  // NP*nbA
    int*    cntB_S   = cntB_D + NP * nbA;                // NP*nbA
    int*    partTotD = cntB_S + NP * nbA;                // NP
    int*    partTotS = partTotD + NP;                    // NP

    size_t req = sizeof(float) * 2 * (size_t)M
               + sizeof(ushort) * ((size_t)(4 + T) * ND + (size_t)T * DD * DD)
               + sizeof(int) * ((size_t)M + 1 + (size_t)E + 64);
    if (ws_size < req) return;
    size_t scratch = 4 * (size_t)E + 2 * ((size_t)E + 2)
                   + sizeof(int) * (2 * (size_t)NP * nbA + 2 * NP + 16);
    if (scratch > sizeof(ushort) * (size_t)T * ND) return;

    int totW = T * DD * DD;
    int nPW = (totW + 1023) / 1024;
    int n8 = (int)(ND / 8);
    int nCvt = (n8 + 1023) / 1024;

    kAF<<<nbA + nPW + nCvt, 1024, 0, stream>>>(ei, E, PSZ, nbA, cntB_D, cntB_S,
                                               W, WT, totW, nPW, x, xb, n8);
    kB1<<<2 * NP, 512, 0, stream>>>(cntB_D, cntB_S, nbA, partTotD, partTotS);
    kC<<<nbA, 1024, 0, stream>>>(ei, ea, E, N, T, PSZ, nbA, cntB_D, cntB_S,
                                 partTotD, partTotS, binD, binS);
    kDE<<<2 * NP, 512, 0, stream>>>(binD, binS, partTotD, partTotS,
                                    N, T, PSZ, M, E, rowptr, isdD2, ep, isdS);

    const ushort* histB[4] = {xb, h1b, h2b, h3b};

    int nodeBlocks = ((size_t)N * 32 + 255) / 256;
    int gemmBlocks = (N + 255) / 256;

    for (int t = 0; t < T; t++) {
        APtrs ap;
        ap.a0 = histB[t];
        ap.a1 = (t >= 1) ? histB[t - 1] : histB[0];
        ap.a2 = (t >= 2) ? histB[t - 2] : histB[0];
        ap.a3 = (t >= 3) ? histB[t - 3] : histB[0];
        dim3 grid(gemmBlocks, t + 1);
        k_gemm_batch<<<grid, 256, 0, stream>>>(ap, WT, isdS, Hb, N);

        bool lastL = (t == T - 1);
        k_agg_fin<<<nodeBlocks, 256, 0, stream>>>(Hb, ep, rowptr, isdD2,
                                                  nu, t, T, t + 1, histB[t],
                                                  lastL ? nullptr : (ushort*)histB[t + 1],
                                                  lastL ? out : nullptr, N);
    }
}

// Round 6
// 406.960 us; speedup vs baseline: 1.4880x; 1.0043x over previous
//
#include <hip/hip_runtime.h>

#define DD 128   // feature dim
#define NP 256   // node partitions
#define EB 4096  // edges per binning block

typedef float4 f4;
typedef __attribute__((ext_vector_type(8))) short bf16x8;
typedef __attribute__((ext_vector_type(4))) float f32x4;

__device__ __forceinline__ short toBf(float f) {
    unsigned u = __float_as_uint(f);
    u += 0x7fff + ((u >> 16) & 1);   // RNE
    return (short)(u >> 16);
}

// ---------------- setup: LDS-binned counting sort (no global atomics) ----------------
// payload packing (32-bit): [31:21] local bucket (dloc*T+k, <2048) | [20:19] k | [18:0] row = k*N+s

__global__ __launch_bounds__(1024) void kAF(const int* __restrict__ ei, int E, int PSZ, int nbA,
                                            int* __restrict__ cntB_D, int* __restrict__ cntB_S,
                                            const float* __restrict__ W, ushort* __restrict__ WT,
                                            int totW, int nPW,
                                            const float* __restrict__ x, ushort* __restrict__ xb,
                                            int n8) {
    __shared__ int hd[NP], hs[NP];
    int tid = threadIdx.x, b = blockIdx.x;
    if (b < nbA) {
        if (tid < NP) { hd[tid] = 0; hs[tid] = 0; }
        __syncthreads();
        int base = b * EB;
        int lim = min(base + EB, E);
        for (int e = base + tid; e < lim; e += 1024) {
            int s = ei[e], d = ei[E + e];
            atomicAdd(&hs[s / PSZ], 1);
            atomicAdd(&hd[d / PSZ], 1);
        }
        __syncthreads();
        if (tid < NP) {
            cntB_D[tid * nbA + b] = hd[tid];
            cntB_S[tid * nbA + b] = hs[tid];
        }
    } else if (b < nbA + nPW) {
        int i = (b - nbA) * 1024 + tid;
        if (i < totW) {
            int k = i >> 14, rem = i & 16383, j = rem >> 7, d = rem & 127;
            WT[i] = (ushort)toBf(W[(size_t)k * 16384 + (size_t)d * DD + j]);  // WT[k][j][d] = W[k][d][j]
        }
    } else {
        int i = (b - nbA - nPW) * 1024 + tid;
        if (i < n8) {
            const f4* q = (const f4*)(x + (size_t)i * 8);
            f4 lo = q[0], hi = q[1];
            bf16x8 r;
            r[0] = toBf(lo.x); r[1] = toBf(lo.y); r[2] = toBf(lo.z); r[3] = toBf(lo.w);
            r[4] = toBf(hi.x); r[5] = toBf(hi.y); r[6] = toBf(hi.z); r[7] = toBf(hi.w);
            *(bf16x8*)(xb + (size_t)i * 8) = r;
        }
    }
}

__global__ __launch_bounds__(512) void kB1(int* __restrict__ cntB_D, int* __restrict__ cntB_S,
                                           int nbA,
                                           int* __restrict__ partTotD, int* __restrict__ partTotS) {
    __shared__ int sh[512];
    int b = blockIdx.x, tid = threadIdx.x;
    int* cntB = (b < NP) ? cntB_D : cntB_S;
    int* partTot = (b < NP) ? partTotD : partTotS;
    int p = (b < NP) ? b : b - NP;
    int v = (tid < nbA) ? cntB[p * nbA + tid] : 0;
    sh[tid] = v; __syncthreads();
    for (int off = 1; off < 512; off <<= 1) {
        int add = (tid >= off) ? sh[tid - off] : 0;
        __syncthreads(); sh[tid] += add; __syncthreads();
    }
    if (tid < nbA) cntB[p * nbA + tid] = sh[tid] - v;   // local exclusive prefix
    if (tid == 511) partTot[p] = sh[511];
}

__global__ __launch_bounds__(1024) void kC(const int* __restrict__ ei, const int* __restrict__ ea,
                                           int E, int N, int T, int PSZ, int nbA,
                                           const int* __restrict__ cntB_D, const int* __restrict__ cntB_S,
                                           const int* __restrict__ partTotD,
                                           const int* __restrict__ partTotS,
                                           int* __restrict__ binD, ushort* __restrict__ binS) {
    __shared__ int pd[NP], ps[NP];
    __shared__ int sc[512];
    int tid = threadIdx.x, b = blockIdx.x;
    if (tid < 512) sc[tid] = (tid < 256) ? partTotD[tid] : partTotS[tid - 256];
    __syncthreads();
    for (int off = 1; off < 256; off <<= 1) {
        int add = 0;
        if (tid < 512 && (tid & 255) >= off) add = sc[tid - off];
        __syncthreads();
        if (tid < 512) sc[tid] += add;
        __syncthreads();
    }
    if (tid < NP) {
        pd[tid] = cntB_D[tid * nbA + b] + (sc[tid] - partTotD[tid]);
        ps[tid] = cntB_S[tid * nbA + b] + (sc[tid + 256] - partTotS[tid]);
    }
    __syncthreads();
    int base = b * EB;
    int lim = min(base + EB, E);
    for (int e = base + tid; e < lim; e += 1024) {
        int s = ei[e], d = ei[E + e], k = ea[e] - 1;
        int dp = d / PSZ, sp = s / PSZ;
        int loc = (d - dp * PSZ) * T + k;
        int posD = atomicAdd(&pd[dp], 1);
        binD[posD] = (loc << 21) | (k << 19) | (k * N + s);
        int posS = atomicAdd(&ps[sp], 1);
        binS[posS] = (ushort)((s - sp * PSZ) * T + k);
    }
}

__global__ __launch_bounds__(512) void kDE(const int* __restrict__ binD,
                                           const ushort* __restrict__ binS,
                                           const int* __restrict__ partTotD,
                                           const int* __restrict__ partTotS,
                                           int N, int T, int PSZ, int M, int E,
                                           int* __restrict__ rowptr, float* __restrict__ isdD2,
                                           int* __restrict__ ep, float* __restrict__ isdS) {
    __shared__ int cnt[4096];
    __shared__ int part[512];
    __shared__ int sc[256];
    int b = blockIdx.x, tid = threadIdx.x;
    bool isD = b < NP;
    int p = isD ? b : b - NP;
    const int* pt = isD ? partTotD : partTotS;
    if (tid < 256) sc[tid] = pt[tid];
    __syncthreads();
    for (int off = 1; off < 256; off <<= 1) {
        int add = (tid < 256 && tid >= off) ? sc[tid - off] : 0;
        __syncthreads();
        if (tid < 256) sc[tid] += add;
        __syncthreads();
    }
    int b1 = sc[p];
    int b0 = b1 - pt[p];
    __syncthreads();
    int nloc = PSZ * T;
    for (int i = tid; i < nloc; i += 512) cnt[i] = 0;
    __syncthreads();
    if (isD) {
        for (int e = b0 + tid; e < b1; e += 512)
            atomicAdd(&cnt[((unsigned)binD[e]) >> 21], 1);
        __syncthreads();
        int CH = (nloc + 511) / 512;
        int c0 = tid * CH, c1 = min(c0 + CH, nloc);
        int s = 0;
        for (int i = c0; i < c1; i++) s += cnt[i];
        part[tid] = s; __syncthreads();
        for (int off = 1; off < 512; off <<= 1) {
            int add = (tid >= off) ? part[tid - off] : 0;
            __syncthreads(); part[tid] += add; __syncthreads();
        }
        int run = ((tid == 0) ? 0 : part[tid - 1]) + b0;
        int gb_base = p * PSZ * T;
        for (int i = c0; i < c1; i++) {
            int v = cnt[i];
            cnt[i] = run;
            int gb = gb_base + i;
            if (gb < M) {
                rowptr[gb] = run;
                isdD2[gb] = rsqrtf((float)max(v, 1));
            }
            run += v;
        }
        __syncthreads();
        for (int e = b0 + tid; e < b1; e += 512) {
            int v = binD[e];
            int pos = atomicAdd(&cnt[((unsigned)v) >> 21], 1);
            ep[pos] = v & 0x1FFFFF;
        }
        if (p == 0 && tid == 0) rowptr[M] = E;
    } else {
        for (int e = b0 + tid; e < b1; e += 512)
            atomicAdd(&cnt[(int)binS[e]], 1);
        __syncthreads();
        int s0 = p * PSZ;
        for (int i = tid; i < nloc; i += 512) {
            int sl = i / T, k = i - sl * T;
            int snode = s0 + sl;
            if (snode < N) isdS[k * N + snode] = rsqrtf((float)max(cnt[i], 1));
        }
    }
}

// ------- batched GEMM (256-row tile, standalone): H'_k0 = diag(isk)*(A_k0 @ W_k0) -------

struct APtrs { const ushort* a0; const ushort* a1; const ushort* a2; const ushort* a3; };

__global__ __launch_bounds__(256) void k_gemm_batch(APtrs ap,
                                                    const ushort* __restrict__ WTb,
                                                    const float* __restrict__ iskb,
                                                    ushort* __restrict__ Hb, int N) {
    __shared__ ushort lW[128 * 128];   // 32 KB
    int k0 = blockIdx.y;
    const ushort* A = (k0 == 0) ? ap.a0 : (k0 == 1) ? ap.a1 : (k0 == 2) ? ap.a2 : ap.a3;
    const ushort* WT = WTb + (size_t)k0 * DD * DD;
    const float* isk = iskb + (size_t)k0 * N;
    ushort* H = Hb + (size_t)k0 * N * DD;

    int tid = threadIdx.x;
#pragma unroll
    for (int i = 0; i < 8; i++) {
        int g = tid + i * 256;
        int row = g >> 4, slot = g & 15;
        bf16x8 v = *(const bf16x8*)(WT + row * DD + slot * 8);
        *(bf16x8*)(lW + row * DD + (slot ^ (row & 7)) * 8) = v;
    }
    __syncthreads();

    int wave = tid >> 6;
    int lane = tid & 63;
    int rlo = lane & 15;
    int khi = lane >> 4;
    int r0 = blockIdx.x * 256 + wave * 64;

    f32x4 acc[4][8];
#pragma unroll
    for (int s = 0; s < 4; s++)
#pragma unroll
        for (int j = 0; j < 8; j++) acc[s][j] = (f32x4){0.f, 0.f, 0.f, 0.f};

    int ca[4];
#pragma unroll
    for (int s = 0; s < 4; s++) {
        int r = r0 + s * 16 + rlo;
        ca[s] = r < N ? r : N - 1;
    }

#pragma unroll
    for (int kk = 0; kk < 4; kk++) {
        int d0 = kk * 32 + khi * 8;
        bf16x8 a[4];
#pragma unroll
        for (int s = 0; s < 4; s++)
            a[s] = *(const bf16x8*)(A + (size_t)ca[s] * DD + d0);
        int q = kk * 4 + khi;
#pragma unroll
        for (int cg = 0; cg < 8; cg++) {
            int row = cg * 16 + rlo;
            bf16x8 b = *(const bf16x8*)(lW + row * DD + (q ^ (rlo & 7)) * 8);
#pragma unroll
            for (int s = 0; s < 4; s++)
                acc[s][cg] = __builtin_amdgcn_mfma_f32_16x16x32_bf16(a[s], b, acc[s][cg], 0, 0, 0);
        }
    }

#pragma unroll
    for (int s = 0; s < 4; s++) {
#pragma unroll
        for (int r = 0; r < 4; r++) {
            int row = r0 + s * 16 + khi * 4 + r;
            if (row < N) {
                float sc = isk[row];
#pragma unroll
                for (int cg = 0; cg < 8; cg++)
                    H[(size_t)row * DD + cg * 16 + rlo] = (ushort)toBf(sc * acc[s][cg][r]);
            }
        }
    }
}

// ------- agg body (shared by k_agg_fin and k_fused) -------

__device__ __forceinline__ float selw(float w0, float w1, float w2, float w3, int k) {
    float a = (k & 1) ? w1 : w0;
    float b = (k & 1) ? w3 : w2;
    return (k & 2) ? b : a;
}

__device__ __forceinline__ void aggBody(
        int aIdx, int tid,
        const ushort* __restrict__ H, const int* __restrict__ ep, const int* __restrict__ rp,
        const float* __restrict__ isdD2, const float* __restrict__ nu,
        int t, int T, int nk, const ushort* __restrict__ hp,
        ushort* __restrict__ hnB, float* __restrict__ outF, int N) {
    int node = (aIdx * 256 + tid) >> 5;
    if (node >= N) return;
    int lane = tid & 31;
    int rbase = node * T;
    int b0 = rp[rbase], b1 = rp[rbase + nk];

    float w0 = nu[t] * isdD2[rbase];
    float w1 = (1 < nk) ? nu[T + t]     * isdD2[rbase + 1] : 0.f;
    float w2 = (2 < nk) ? nu[2 * T + t] * isdD2[rbase + 2] : 0.f;
    float w3 = (3 < nk) ? nu[3 * T + t] * isdD2[rbase + 3] : 0.f;

    const char* Hc = (const char*)H;
    unsigned lb = (unsigned)lane << 3;

    float sx = 0.f, sy = 0.f, sz = 0.f, sw = 0.f;
    int e = b0;

#define DEC(P, O, C) \
    O = ((((unsigned)(P)) & 0x7FFFFu) << 8) | lb; \
    C = selw(w0, w1, w2, w3, (P) >> 19);

#define ACC(G, C) { \
    float f0 = __uint_as_float((G).x << 16); \
    float f1 = __uint_as_float((G).x & 0xffff0000u); \
    float f2 = __uint_as_float((G).y << 16); \
    float f3 = __uint_as_float((G).y & 0xffff0000u); \
    sx = fmaf((C), f0, sx); sy = fmaf((C), f1, sy); \
    sz = fmaf((C), f2, sz); sw = fmaf((C), f3, sw); }

    for (; e + 7 < b1; e += 8) {
        int p0 = ep[e],     p1 = ep[e + 1], p2 = ep[e + 2], p3 = ep[e + 3];
        int p4 = ep[e + 4], p5 = ep[e + 5], p6 = ep[e + 6], p7 = ep[e + 7];
        unsigned o0, o1, o2, o3, o4, o5, o6, o7;
        float c0, c1, c2, c3, c4, c5, c6, c7;
        DEC(p0, o0, c0) DEC(p1, o1, c1) DEC(p2, o2, c2) DEC(p3, o3, c3)
        DEC(p4, o4, c4) DEC(p5, o5, c5) DEC(p6, o6, c6) DEC(p7, o7, c7)
        uint2 g0 = *(const uint2*)(Hc + o0);
        uint2 g1 = *(const uint2*)(Hc + o1);
        uint2 g2 = *(const uint2*)(Hc + o2);
        uint2 g3 = *(const uint2*)(Hc + o3);
        uint2 g4 = *(const uint2*)(Hc + o4);
        uint2 g5 = *(const uint2*)(Hc + o5);
        uint2 g6 = *(const uint2*)(Hc + o6);
        uint2 g7 = *(const uint2*)(Hc + o7);
        ACC(g0, c0) ACC(g1, c1) ACC(g2, c2) ACC(g3, c3)
        ACC(g4, c4) ACC(g5, c5) ACC(g6, c6) ACC(g7, c7)
    }
    if (e + 3 < b1) {
        int p0 = ep[e], p1 = ep[e + 1], p2 = ep[e + 2], p3 = ep[e + 3];
        unsigned o0, o1, o2, o3;
        float c0, c1, c2, c3;
        DEC(p0, o0, c0) DEC(p1, o1, c1) DEC(p2, o2, c2) DEC(p3, o3, c3)
        uint2 g0 = *(const uint2*)(Hc + o0);
        uint2 g1 = *(const uint2*)(Hc + o1);
        uint2 g2 = *(const uint2*)(Hc + o2);
        uint2 g3 = *(const uint2*)(Hc + o3);
        ACC(g0, c0) ACC(g1, c1) ACC(g2, c2) ACC(g3, c3)
        e += 4;
    }
    for (; e < b1; e++) {
        int p0 = ep[e];
        unsigned o0; float c0;
        DEC(p0, o0, c0)
        uint2 g0 = *(const uint2*)(Hc + o0);
        ACC(g0, c0)
    }
#undef DEC
#undef ACC

    unsigned nodeOff = ((unsigned)node << 8) | lb;
    uint2 hv = *(const uint2*)((const char*)hp + nodeOff);
    float vx = __uint_as_float(hv.x << 16)         + fmaxf(sx, 0.f);
    float vy = __uint_as_float(hv.x & 0xffff0000u) + fmaxf(sy, 0.f);
    float vz = __uint_as_float(hv.y << 16)         + fmaxf(sz, 0.f);
    float vw = __uint_as_float(hv.y & 0xffff0000u) + fmaxf(sw, 0.f);
    float ss = vx * vx + vy * vy + vz * vz + vw * vw;
#pragma unroll
    for (int off = 16; off; off >>= 1) ss += __shfl_xor(ss, off, 32);
    float inv = 1.f / fmaxf(sqrtf(ss), 1e-12f);
    vx *= inv; vy *= inv; vz *= inv; vw *= inv;
    if (outF) {
        f4 o; o.x = vx; o.y = vy; o.z = vz; o.w = vw;
        *(f4*)((char*)outF + (((size_t)node << 9) | ((size_t)lane << 4))) = o;
    } else {
        uint lo = ((unsigned)(unsigned short)toBf(vx)) | (((unsigned)(unsigned short)toBf(vy)) << 16);
        uint hi = ((unsigned)(unsigned short)toBf(vz)) | (((unsigned)(unsigned short)toBf(vw)) << 16);
        uint2 ob; ob.x = lo; ob.y = hi;
        *(uint2*)((char*)hnB + nodeOff) = ob;
    }
}

__global__ __launch_bounds__(256) void k_agg_fin(
        const ushort* __restrict__ H, const int* __restrict__ ep, const int* __restrict__ rp,
        const float* __restrict__ isdD2, const float* __restrict__ nu,
        int t, int T, int nk, const ushort* __restrict__ hp,
        ushort* __restrict__ hnB, float* __restrict__ outF, int N) {
    aggBody(blockIdx.x, threadIdx.x, H, ep, rp, isdD2, nu, t, T, nk, hp, hnB, outF, N);
}

// ------- lean 64-row GEMM body for the fused kernel (16 KB LDS, 2-stage W) -------

__device__ __forceinline__ void gemm64Body(int bx, int tid,
                                           const ushort* __restrict__ A,
                                           const ushort* __restrict__ WT,
                                           const float* __restrict__ isk,
                                           ushort* __restrict__ H, int N, ushort* lW) {
    int wave = tid >> 6;
    int lane = tid & 63;
    int rlo = lane & 15;
    int khi = lane >> 4;
    int r0 = bx * 64 + wave * 16;

    f32x4 acc[8];
#pragma unroll
    for (int j = 0; j < 8; j++) acc[j] = (f32x4){0.f, 0.f, 0.f, 0.f};

    int r = r0 + rlo;
    int ca = r < N ? r : N - 1;

#pragma unroll
    for (int stage = 0; stage < 2; stage++) {
        __syncthreads();
#pragma unroll
        for (int i = 0; i < 4; i++) {
            int g = tid + i * 256;
            int row = g >> 4, slot = g & 15;
            bf16x8 v = *(const bf16x8*)(WT + (stage * 64 + row) * DD + slot * 8);
            *(bf16x8*)(lW + row * DD + (slot ^ (row & 7)) * 8) = v;
        }
        __syncthreads();
#pragma unroll
        for (int kk = 0; kk < 4; kk++) {
            int d0 = kk * 32 + khi * 8;
            bf16x8 a = *(const bf16x8*)(A + (size_t)ca * DD + d0);
            int q = kk * 4 + khi;
#pragma unroll
            for (int cg4 = 0; cg4 < 4; cg4++) {
                int row2 = cg4 * 16 + rlo;
                bf16x8 b = *(const bf16x8*)(lW + row2 * DD + (q ^ (rlo & 7)) * 8);
                acc[stage * 4 + cg4] =
                    __builtin_amdgcn_mfma_f32_16x16x32_bf16(a, b, acc[stage * 4 + cg4], 0, 0, 0);
            }
        }
    }

#pragma unroll
    for (int rr = 0; rr < 4; rr++) {
        int row = r0 + khi * 4 + rr;
        if (row < N) {
            float sc = isk[row];
#pragma unroll
            for (int cg = 0; cg < 8; cg++)
                H[(size_t)row * DD + cg * 16 + rlo] = (ushort)toBf(sc * acc[cg][rr]);
        }
    }
}

// ------- fused: agg layer t  +  GEMM slices k0=1..nsl for layer t+1 -------

__global__ __launch_bounds__(256, 5) void k_fused(
        const ushort* __restrict__ Hcur, const int* __restrict__ ep, const int* __restrict__ rp,
        const float* __restrict__ isdD2, const float* __restrict__ nu,
        int t, int T, int nk, const ushort* __restrict__ hp, ushort* __restrict__ hnB, int N,
        int nodeBlocks,
        const ushort* __restrict__ A1, const ushort* __restrict__ A2, const ushort* __restrict__ A3,
        const ushort* __restrict__ WTb, const float* __restrict__ iskb,
        ushort* __restrict__ Hnext, int nsl, int gb64) {
    __shared__ ushort lW[64 * 128];   // 16 KB
    int b = blockIdx.x, tid = threadIdx.x;
    long G = (long)nsl * gb64;
    int total = nodeBlocks + (int)G;
    int gAt = (int)(((long)b * G) / total);
    int gNext = (int)(((long)(b + 1) * G) / total);
    if (gNext > gAt) {
        // GEMM role (Bresenham-spread through dispatch order)
        int gid = gAt;
        int sl = 0, bx = gid;
        if (bx >= gb64) { sl = 1; bx -= gb64; }
        if (bx >= gb64) { sl = 2; bx -= gb64; }
        const ushort* A = (sl == 0) ? A1 : (sl == 1) ? A2 : A3;
        int k0 = sl + 1;
        gemm64Body(bx, tid, A, WTb + (size_t)k0 * DD * DD, iskb + (size_t)k0 * N,
                   Hnext + (size_t)k0 * N * DD, N, lW);
    } else {
        int aIdx = b - gAt;
        aggBody(aIdx, tid, Hcur, ep, rp, isdD2, nu, t, T, nk, hp, hnB, nullptr, N);
    }
}

// ---------------- driver ----------------

extern "C" void kernel_launch(void* const* d_in, const int* in_sizes, int n_in,
                              void* d_out, int out_size, void* d_ws, size_t ws_size,
                              hipStream_t stream) {
    const float* x  = (const float*)d_in[0];
    const int*   ei = (const int*)d_in[1];
    const int*   ea = (const int*)d_in[2];
    const float* W  = (const float*)d_in[3];
    const float* nu = (const float*)d_in[4];
    float* out = (float*)d_out;

    int N = in_sizes[0] / DD;
    int E = in_sizes[1] / 2;
    int T = in_sizes[3] / (DD * DD);
    int M = T * N;
    size_t ND = (size_t)N * DD;

    int PSZ = (N + NP - 1) / NP;
    if (PSZ * T > 2048) return;
    if ((long)T * N > (1L << 19)) return;
    int nbA = (E + EB - 1) / EB;
    if (nbA > 512) return;

    size_t reqSerial = sizeof(float) * 2 * (size_t)M
                     + sizeof(ushort) * ((size_t)(4 + T) * ND + (size_t)T * DD * DD)
                     + sizeof(int) * ((size_t)M + 1 + (size_t)E + 64);
    size_t reqFused = reqSerial + sizeof(ushort) * (size_t)T * ND;
    if (ws_size < reqSerial) return;
    bool fused = (T == 4) && (ws_size >= reqFused);

    // workspace layout
    float*  isdS  = (float*)d_ws;            // M f32
    float*  isdD2 = isdS + M;                // M f32
    ushort* xb    = (ushort*)(isdD2 + M);    // ND bf16
    ushort* h1b   = xb + ND;
    ushort* h2b   = h1b + ND;
    ushort* h3b   = h2b + ND;
    ushort* HbA   = h3b + ND;                // T*ND bf16
    ushort* HbB   = fused ? (HbA + (size_t)T * ND) : HbA;   // T*ND bf16 (fused only)
    ushort* WT    = HbB + (size_t)T * ND;    // T*128*128 bf16
    int* rowptr   = (int*)(WT + (size_t)T * DD * DD);  // M+1
    int* ep       = rowptr + M + 1;          // E
    // setup scratch aliases HbA (setup strictly precedes all H writes)
    int*    binD     = (int*)HbA;                        // E
    ushort* binS     = (ushort*)(binD + E);              // E
    int*    cntB_D   = (int*)(binS + (((size_t)E + 1) & ~(size_t)1));
    int*    cntB_S   = cntB_D + NP * nbA;
    int*    partTotD = cntB_S + NP * nbA;
    int*    partTotS = partTotD + NP;

    size_t scratch = 4 * (size_t)E + 2 * ((size_t)E + 2)
                   + sizeof(int) * (2 * (size_t)NP * nbA + 2 * NP + 16);
    if (scratch > sizeof(ushort) * (size_t)T * ND) return;

    int totW = T * DD * DD;
    int nPW = (totW + 1023) / 1024;
    int n8 = (int)(ND / 8);
    int nCvt = (n8 + 1023) / 1024;

    kAF<<<nbA + nPW + nCvt, 1024, 0, stream>>>(ei, E, PSZ, nbA, cntB_D, cntB_S,
                                               W, WT, totW, nPW, x, xb, n8);
    kB1<<<2 * NP, 512, 0, stream>>>(cntB_D, cntB_S, nbA, partTotD, partTotS);
    kC<<<nbA, 1024, 0, stream>>>(ei, ea, E, N, T, PSZ, nbA, cntB_D, cntB_S,
                                 partTotD, partTotS, binD, binS);
    kDE<<<2 * NP, 512, 0, stream>>>(binD, binS, partTotD, partTotS,
                                    N, T, PSZ, M, E, rowptr, isdD2, ep, isdS);

    const ushort* histB[4] = {xb, h1b, h2b, h3b};
    int nodeBlocks = ((size_t)N * 32 + 255) / 256;
    int gb256 = (N + 255) / 256;
    int gb64 = (N + 63) / 64;

    if (fused) {
        // layer-0 GEMM (slice k0=0 only)
        APtrs ap0; ap0.a0 = xb; ap0.a1 = xb; ap0.a2 = xb; ap0.a3 = xb;
        k_gemm_batch<<<dim3(gb256, 1), 256, 0, stream>>>(ap0, WT, isdS, HbA, N);
        for (int t = 0; t < T - 1; t++) {
            ushort* Hcur = (t & 1) ? HbB : HbA;
            ushort* Hnext = (t & 1) ? HbA : HbB;
            int nsl = t + 1;   // slices k0=1..t+1 for layer t+1
            const ushort* A1 = histB[t];
            const ushort* A2 = (t >= 1) ? histB[t - 1] : histB[0];
            const ushort* A3 = (t >= 2) ? histB[t - 2] : histB[0];
            int totalBlocks = nodeBlocks + nsl * gb64;
            k_fused<<<totalBlocks, 256, 0, stream>>>(Hcur, ep, rowptr, isdD2,
                                                     nu, t, T, t + 1, histB[t],
                                                     (ushort*)histB[t + 1], N, nodeBlocks,
                                                     A1, A2, A3, WT, isdS, Hnext, nsl, gb64);
            // slice k0=0 for layer t+1 (depends on hist[t+1])
            APtrs aps; aps.a0 = histB[t + 1]; aps.a1 = aps.a0; aps.a2 = aps.a0; aps.a3 = aps.a0;
            k_gemm_batch<<<dim3(gb256, 1), 256, 0, stream>>>(aps, WT, isdS, Hnext, N);
        }
        ushort* Hlast = ((T - 1) & 1) ? HbB : HbA;
        k_agg_fin<<<nodeBlocks, 256, 0, stream>>>(Hlast, ep, rowptr, isdD2,
                                                  nu, T - 1, T, T, histB[T - 1],
                                                  nullptr, out, N);
    } else {
        for (int t = 0; t < T; t++) {
            APtrs ap;
            ap.a0 = histB[t];
            ap.a1 = (t >= 1) ? histB[t - 1] : histB[0];
            ap.a2 = (t >= 2) ? histB[t - 2] : histB[0];
            ap.a3 = (t >= 3) ? histB[t - 3] : histB[0];
            dim3 grid(gb256, t + 1);
            k_gemm_batch<<<grid, 256, 0, stream>>>(ap, WT, isdS, HbA, N);
            bool lastL = (t == T - 1);
            k_agg_fin<<<nodeBlocks, 256, 0, stream>>>(HbA, ep, rowptr, isdD2,
                                                      nu, t, T, t + 1, histB[t],
                                                      lastL ? nullptr : (ushort*)histB[t + 1],
                                                      lastL ? out : nullptr, N);
        }
    }
}

// Round 8
// 406.921 us; speedup vs baseline: 1.4882x; 1.0001x over previous
//
#include <hip/hip_runtime.h>

#define DD 128   // feature dim
#define NP 256   // node partitions
#define EB 4096  // edges per binning block

typedef float4 f4;
typedef __attribute__((ext_vector_type(8))) short bf16x8;
typedef __attribute__((ext_vector_type(4))) float f32x4;

__device__ __forceinline__ short toBf(float f) {
    unsigned u = __float_as_uint(f);
    u += 0x7fff + ((u >> 16) & 1);   // RNE
    return (short)(u >> 16);
}

// ---------------- setup: LDS-binned counting sort (no global atomics) ----------------
// payload packing (32-bit): [31:21] local bucket (dloc*T+k, <2048) | [20:19] k | [18:0] row = k*N+s

__global__ __launch_bounds__(1024) void kAF(const int* __restrict__ ei, int E, int PSZ, int nbA,
                                            int* __restrict__ cntB_D, int* __restrict__ cntB_S,
                                            const float* __restrict__ W, ushort* __restrict__ WT,
                                            int totW, int nPW,
                                            const float* __restrict__ x, ushort* __restrict__ xb,
                                            int n8) {
    __shared__ int hd[NP], hs[NP];
    int tid = threadIdx.x, b = blockIdx.x;
    if (b < nbA) {
        if (tid < NP) { hd[tid] = 0; hs[tid] = 0; }
        __syncthreads();
        int base = b * EB;
        int lim = min(base + EB, E);
        for (int e = base + tid; e < lim; e += 1024) {
            int s = ei[e], d = ei[E + e];
            atomicAdd(&hs[s / PSZ], 1);
            atomicAdd(&hd[d / PSZ], 1);
        }
        __syncthreads();
        if (tid < NP) {
            cntB_D[tid * nbA + b] = hd[tid];
            cntB_S[tid * nbA + b] = hs[tid];
        }
    } else if (b < nbA + nPW) {
        int i = (b - nbA) * 1024 + tid;
        if (i < totW) {
            int k = i >> 14, rem = i & 16383, j = rem >> 7, d = rem & 127;
            WT[i] = (ushort)toBf(W[(size_t)k * 16384 + (size_t)d * DD + j]);  // WT[k][j][d] = W[k][d][j]
        }
    } else {
        int i = (b - nbA - nPW) * 1024 + tid;
        if (i < n8) {
            const f4* q = (const f4*)(x + (size_t)i * 8);
            f4 lo = q[0], hi = q[1];
            bf16x8 r;
            r[0] = toBf(lo.x); r[1] = toBf(lo.y); r[2] = toBf(lo.z); r[3] = toBf(lo.w);
            r[4] = toBf(hi.x); r[5] = toBf(hi.y); r[6] = toBf(hi.z); r[7] = toBf(hi.w);
            *(bf16x8*)(xb + (size_t)i * 8) = r;
        }
    }
}

__global__ __launch_bounds__(512) void kB1(int* __restrict__ cntB_D, int* __restrict__ cntB_S,
                                           int nbA,
                                           int* __restrict__ partTotD, int* __restrict__ partTotS) {
    __shared__ int sh[512];
    int b = blockIdx.x, tid = threadIdx.x;
    int* cntB = (b < NP) ? cntB_D : cntB_S;
    int* partTot = (b < NP) ? partTotD : partTotS;
    int p = (b < NP) ? b : b - NP;
    int v = (tid < nbA) ? cntB[p * nbA + tid] : 0;
    sh[tid] = v; __syncthreads();
    for (int off = 1; off < 512; off <<= 1) {
        int add = (tid >= off) ? sh[tid - off] : 0;
        __syncthreads(); sh[tid] += add; __syncthreads();
    }
    if (tid < nbA) cntB[p * nbA + tid] = sh[tid] - v;   // local exclusive prefix
    if (tid == 511) partTot[p] = sh[511];
}

__global__ __launch_bounds__(1024) void kC(const int* __restrict__ ei, const int* __restrict__ ea,
                                           int E, int N, int T, int PSZ, int nbA,
                                           const int* __restrict__ cntB_D, const int* __restrict__ cntB_S,
                                           const int* __restrict__ partTotD,
                                           const int* __restrict__ partTotS,
                                           int* __restrict__ binD, ushort* __restrict__ binS) {
    __shared__ int pd[NP], ps[NP];
    __shared__ int sc[512];
    int tid = threadIdx.x, b = blockIdx.x;
    if (tid < 512) sc[tid] = (tid < 256) ? partTotD[tid] : partTotS[tid - 256];
    __syncthreads();
    for (int off = 1; off < 256; off <<= 1) {
        int add = 0;
        if (tid < 512 && (tid & 255) >= off) add = sc[tid - off];
        __syncthreads();
        if (tid < 512) sc[tid] += add;
        __syncthreads();
    }
    if (tid < NP) {
        pd[tid] = cntB_D[tid * nbA + b] + (sc[tid] - partTotD[tid]);
        ps[tid] = cntB_S[tid * nbA + b] + (sc[tid + 256] - partTotS[tid]);
    }
    __syncthreads();
    int base = b * EB;
    int lim = min(base + EB, E);
    for (int e = base + tid; e < lim; e += 1024) {
        int s = ei[e], d = ei[E + e], k = ea[e] - 1;
        int dp = d / PSZ, sp = s / PSZ;
        int loc = (d - dp * PSZ) * T + k;
        int posD = atomicAdd(&pd[dp], 1);
        binD[posD] = (loc << 21) | (k << 19) | (k * N + s);
        int posS = atomicAdd(&ps[sp], 1);
        binS[posS] = (ushort)((s - sp * PSZ) * T + k);
    }
}

__global__ __launch_bounds__(512) void kDE(const int* __restrict__ binD,
                                           const ushort* __restrict__ binS,
                                           const int* __restrict__ partTotD,
                                           const int* __restrict__ partTotS,
                                           int N, int T, int PSZ, int M, int E,
                                           int* __restrict__ rowptr, float* __restrict__ isdD2,
                                           int* __restrict__ ep, float* __restrict__ isdS) {
    __shared__ int cnt[4096];
    __shared__ int part[512];
    __shared__ int sc[256];
    int b = blockIdx.x, tid = threadIdx.x;
    bool isD = b < NP;
    int p = isD ? b : b - NP;
    const int* pt = isD ? partTotD : partTotS;
    if (tid < 256) sc[tid] = pt[tid];
    __syncthreads();
    for (int off = 1; off < 256; off <<= 1) {
        int add = (tid < 256 && tid >= off) ? sc[tid - off] : 0;
        __syncthreads();
        if (tid < 256) sc[tid] += add;
        __syncthreads();
    }
    int b1 = sc[p];
    int b0 = b1 - pt[p];
    __syncthreads();
    int nloc = PSZ * T;
    for (int i = tid; i < nloc; i += 512) cnt[i] = 0;
    __syncthreads();
    if (isD) {
        for (int e = b0 + tid; e < b1; e += 512)
            atomicAdd(&cnt[((unsigned)binD[e]) >> 21], 1);
        __syncthreads();
        int CH = (nloc + 511) / 512;
        int c0 = tid * CH, c1 = min(c0 + CH, nloc);
        int s = 0;
        for (int i = c0; i < c1; i++) s += cnt[i];
        part[tid] = s; __syncthreads();
        for (int off = 1; off < 512; off <<= 1) {
            int add = (tid >= off) ? part[tid - off] : 0;
            __syncthreads(); part[tid] += add; __syncthreads();
        }
        int run = ((tid == 0) ? 0 : part[tid - 1]) + b0;
        int gb_base = p * PSZ * T;
        for (int i = c0; i < c1; i++) {
            int v = cnt[i];
            cnt[i] = run;
            int gb = gb_base + i;
            if (gb < M) {
                rowptr[gb] = run;
                isdD2[gb] = rsqrtf((float)max(v, 1));
            }
            run += v;
        }
        __syncthreads();
        for (int e = b0 + tid; e < b1; e += 512) {
            int v = binD[e];
            int pos = atomicAdd(&cnt[((unsigned)v) >> 21], 1);
            ep[pos] = v & 0x1FFFFF;
        }
        if (p == 0 && tid == 0) rowptr[M] = E;
    } else {
        for (int e = b0 + tid; e < b1; e += 512)
            atomicAdd(&cnt[(int)binS[e]], 1);
        __syncthreads();
        int s0 = p * PSZ;
        for (int i = tid; i < nloc; i += 512) {
            int sl = i / T, k = i - sl * T;
            int snode = s0 + sl;
            if (snode < N) isdS[k * N + snode] = rsqrtf((float)max(cnt[i], 1));
        }
    }
}

// ------- multi-k GEMM: for A = hist[j], compute P[i] = diag(isk_i)*(A @ W_i), i=0..nk-1 -------
// 128 rows/block, A-tile cached in registers across the i-loop (A read from HBM once).

__global__ __launch_bounds__(256) void k_gemm_multi(
        const ushort* __restrict__ A, const ushort* __restrict__ WTb,
        const float* __restrict__ iskb,
        ushort* __restrict__ d0, ushort* __restrict__ d1,
        ushort* __restrict__ d2, ushort* __restrict__ d3,
        int nk, int N) {
    __shared__ ushort lW[128 * 128];   // 32 KB
    int tid = threadIdx.x;
    int wave = tid >> 6;
    int lane = tid & 63;
    int rlo = lane & 15;
    int khi = lane >> 4;
    int r0 = blockIdx.x * 128 + wave * 32;

    int ca[2];
#pragma unroll
    for (int s = 0; s < 2; s++) {
        int r = r0 + s * 16 + rlo;
        ca[s] = r < N ? r : N - 1;
    }
    // cache A fragments: 2 strips x 4 K-chunks x 16B = 32 VGPR
    bf16x8 a[2][4];
#pragma unroll
    for (int s = 0; s < 2; s++)
#pragma unroll
        for (int kk = 0; kk < 4; kk++)
            a[s][kk] = *(const bf16x8*)(A + (size_t)ca[s] * DD + kk * 32 + khi * 8);

#pragma unroll
    for (int i = 0; i < 4; i++) {
        if (i >= nk) break;
        ushort* H = (i == 0) ? d0 : (i == 1) ? d1 : (i == 2) ? d2 : d3;
        const ushort* WT = WTb + (size_t)i * DD * DD;
        const float* isk = iskb + (size_t)i * N;

        __syncthreads();
#pragma unroll
        for (int g8 = 0; g8 < 8; g8++) {
            int g = tid + g8 * 256;
            int row = g >> 4, slot = g & 15;
            bf16x8 v = *(const bf16x8*)(WT + row * DD + slot * 8);
            *(bf16x8*)(lW + row * DD + (slot ^ (row & 7)) * 8) = v;
        }
        __syncthreads();

        f32x4 acc[2][8];
#pragma unroll
        for (int s = 0; s < 2; s++)
#pragma unroll
            for (int j = 0; j < 8; j++) acc[s][j] = (f32x4){0.f, 0.f, 0.f, 0.f};

#pragma unroll
        for (int kk = 0; kk < 4; kk++) {
            int q = kk * 4 + khi;
#pragma unroll
            for (int cg = 0; cg < 8; cg++) {
                int row = cg * 16 + rlo;
                bf16x8 b = *(const bf16x8*)(lW + row * DD + (q ^ (rlo & 7)) * 8);
#pragma unroll
                for (int s = 0; s < 2; s++)
                    acc[s][cg] = __builtin_amdgcn_mfma_f32_16x16x32_bf16(a[s][kk], b, acc[s][cg], 0, 0, 0);
            }
        }

#pragma unroll
        for (int s = 0; s < 2; s++) {
#pragma unroll
            for (int r = 0; r < 4; r++) {
                int row = r0 + s * 16 + khi * 4 + r;
                if (row < N) {
                    float sc = isk[row];
#pragma unroll
                    for (int cg = 0; cg < 8; cg++)
                        H[(size_t)row * DD + cg * 16 + rlo] = (ushort)toBf(sc * acc[s][cg][r]);
                }
            }
        }
    }
}

// ------- fallback batched GEMM (256-row tile): H'_k0 = diag(isk)*(A_k0 @ W_k0) -------

struct APtrs { const ushort* a0; const ushort* a1; const ushort* a2; const ushort* a3; };

__global__ __launch_bounds__(256) void k_gemm_batch(APtrs ap,
                                                    const ushort* __restrict__ WTb,
                                                    const float* __restrict__ iskb,
                                                    ushort* __restrict__ Hb, int N) {
    __shared__ ushort lW[128 * 128];   // 32 KB
    int k0 = blockIdx.y;
    const ushort* A = (k0 == 0) ? ap.a0 : (k0 == 1) ? ap.a1 : (k0 == 2) ? ap.a2 : ap.a3;
    const ushort* WT = WTb + (size_t)k0 * DD * DD;
    const float* isk = iskb + (size_t)k0 * N;
    ushort* H = Hb + (size_t)k0 * N * DD;

    int tid = threadIdx.x;
#pragma unroll
    for (int i = 0; i < 8; i++) {
        int g = tid + i * 256;
        int row = g >> 4, slot = g & 15;
        bf16x8 v = *(const bf16x8*)(WT + row * DD + slot * 8);
        *(bf16x8*)(lW + row * DD + (slot ^ (row & 7)) * 8) = v;
    }
    __syncthreads();

    int wave = tid >> 6;
    int lane = tid & 63;
    int rlo = lane & 15;
    int khi = lane >> 4;
    int r0 = blockIdx.x * 256 + wave * 64;

    f32x4 acc[4][8];
#pragma unroll
    for (int s = 0; s < 4; s++)
#pragma unroll
        for (int j = 0; j < 8; j++) acc[s][j] = (f32x4){0.f, 0.f, 0.f, 0.f};

    int ca[4];
#pragma unroll
    for (int s = 0; s < 4; s++) {
        int r = r0 + s * 16 + rlo;
        ca[s] = r < N ? r : N - 1;
    }

#pragma unroll
    for (int kk = 0; kk < 4; kk++) {
        int d0 = kk * 32 + khi * 8;
        bf16x8 a[4];
#pragma unroll
        for (int s = 0; s < 4; s++)
            a[s] = *(const bf16x8*)(A + (size_t)ca[s] * DD + d0);
        int q = kk * 4 + khi;
#pragma unroll
        for (int cg = 0; cg < 8; cg++) {
            int row = cg * 16 + rlo;
            bf16x8 b = *(const bf16x8*)(lW + row * DD + (q ^ (rlo & 7)) * 8);
#pragma unroll
            for (int s = 0; s < 4; s++)
                acc[s][cg] = __builtin_amdgcn_mfma_f32_16x16x32_bf16(a[s], b, acc[s][cg], 0, 0, 0);
        }
    }

#pragma unroll
    for (int s = 0; s < 4; s++) {
#pragma unroll
        for (int r = 0; r < 4; r++) {
            int row = r0 + s * 16 + khi * 4 + r;
            if (row < N) {
                float sc = isk[row];
#pragma unroll
                for (int cg = 0; cg < 8; cg++)
                    H[(size_t)row * DD + cg * 16 + rlo] = (ushort)toBf(sc * acc[s][cg][r]);
            }
        }
    }
}

// ------- per-layer agg: gather-sum over contiguous segment; out = l2norm(hist + relu(acc)) -------

__device__ __forceinline__ float selw(float w0, float w1, float w2, float w3, int k) {
    float a = (k & 1) ? w1 : w0;
    float b = (k & 1) ? w3 : w2;
    return (k & 2) ? b : a;
}

__global__ __launch_bounds__(256) void k_agg_fin(
        const ushort* __restrict__ H,        // layer buffer: slice i at i*N*DD, row = i*N+s
        const int* __restrict__ ep,          // packed payloads (k<<19|row), (dst,k)-bucket order
        const int* __restrict__ rp,          // M+1 rowptr, bucket = d*T+k
        const float* __restrict__ isdD2,     // M, d*T+k
        const float* __restrict__ nu, int t, int T, int nk,
        const ushort* __restrict__ hp,       // residual input (bf16)
        ushort* __restrict__ hnB,            // bf16 hist output (t < T-1)
        float* __restrict__ outF,            // f32 output (t == T-1), else null
        int N) {
    int node = (blockIdx.x * blockDim.x + threadIdx.x) >> 5;
    if (node >= N) return;
    int lane = threadIdx.x & 31;
    int rbase = node * T;
    int b0 = rp[rbase], b1 = rp[rbase + nk];

    float w0 = nu[t] * isdD2[rbase];
    float w1 = (1 < nk) ? nu[T + t]     * isdD2[rbase + 1] : 0.f;
    float w2 = (2 < nk) ? nu[2 * T + t] * isdD2[rbase + 2] : 0.f;
    float w3 = (3 < nk) ? nu[3 * T + t] * isdD2[rbase + 3] : 0.f;

    const char* Hc = (const char*)H;
    unsigned lb = (unsigned)lane << 3;   // byte offset of this lane's 8B within a 256B row

    float sx = 0.f, sy = 0.f, sz = 0.f, sw = 0.f;
    int e = b0;

#define DEC(P, O, C) \
    O = ((((unsigned)(P)) & 0x7FFFFu) << 8) | lb; \
    C = selw(w0, w1, w2, w3, (P) >> 19);

#define ACC(G, C) { \
    float f0 = __uint_as_float((G).x << 16); \
    float f1 = __uint_as_float((G).x & 0xffff0000u); \
    float f2 = __uint_as_float((G).y << 16); \
    float f3 = __uint_as_float((G).y & 0xffff0000u); \
    sx = fmaf((C), f0, sx); sy = fmaf((C), f1, sy); \
    sz = fmaf((C), f2, sz); sw = fmaf((C), f3, sw); }

    for (; e + 7 < b1; e += 8) {
        int p0 = ep[e],     p1 = ep[e + 1], p2 = ep[e + 2], p3 = ep[e + 3];
        int p4 = ep[e + 4], p5 = ep[e + 5], p6 = ep[e + 6], p7 = ep[e + 7];
        unsigned o0, o1, o2, o3, o4, o5, o6, o7;
        float c0, c1, c2, c3, c4, c5, c6, c7;
        DEC(p0, o0, c0) DEC(p1, o1, c1) DEC(p2, o2, c2) DEC(p3, o3, c3)
        DEC(p4, o4, c4) DEC(p5, o5, c5) DEC(p6, o6, c6) DEC(p7, o7, c7)
        uint2 g0 = *(const uint2*)(Hc + o0);
        uint2 g1 = *(const uint2*)(Hc + o1);
        uint2 g2 = *(const uint2*)(Hc + o2);
        uint2 g3 = *(const uint2*)(Hc + o3);
        uint2 g4 = *(const uint2*)(Hc + o4);
        uint2 g5 = *(const uint2*)(Hc + o5);
        uint2 g6 = *(const uint2*)(Hc + o6);
        uint2 g7 = *(const uint2*)(Hc + o7);
        ACC(g0, c0) ACC(g1, c1) ACC(g2, c2) ACC(g3, c3)
        ACC(g4, c4) ACC(g5, c5) ACC(g6, c6) ACC(g7, c7)
    }
    if (e + 3 < b1) {
        int p0 = ep[e], p1 = ep[e + 1], p2 = ep[e + 2], p3 = ep[e + 3];
        unsigned o0, o1, o2, o3;
        float c0, c1, c2, c3;
        DEC(p0, o0, c0) DEC(p1, o1, c1) DEC(p2, o2, c2) DEC(p3, o3, c3)
        uint2 g0 = *(const uint2*)(Hc + o0);
        uint2 g1 = *(const uint2*)(Hc + o1);
        uint2 g2 = *(const uint2*)(Hc + o2);
        uint2 g3 = *(const uint2*)(Hc + o3);
        ACC(g0, c0) ACC(g1, c1) ACC(g2, c2) ACC(g3, c3)
        e += 4;
    }
    for (; e < b1; e++) {
        int p0 = ep[e];
        unsigned o0; float c0;
        DEC(p0, o0, c0)
        uint2 g0 = *(const uint2*)(Hc + o0);
        ACC(g0, c0)
    }
#undef DEC
#undef ACC

    unsigned nodeOff = ((unsigned)node << 8) | lb;
    uint2 hv = *(const uint2*)((const char*)hp + nodeOff);
    float vx = __uint_as_float(hv.x << 16)         + fmaxf(sx, 0.f);
    float vy = __uint_as_float(hv.x & 0xffff0000u) + fmaxf(sy, 0.f);
    float vz = __uint_as_float(hv.y << 16)         + fmaxf(sz, 0.f);
    float vw = __uint_as_float(hv.y & 0xffff0000u) + fmaxf(sw, 0.f);
    float ss = vx * vx + vy * vy + vz * vz + vw * vw;
#pragma unroll
    for (int off = 16; off; off >>= 1) ss += __shfl_xor(ss, off, 32);
    float inv = 1.f / fmaxf(sqrtf(ss), 1e-12f);
    vx *= inv; vy *= inv; vz *= inv; vw *= inv;
    if (outF) {
        f4 o; o.x = vx; o.y = vy; o.z = vz; o.w = vw;
        *(f4*)((char*)outF + (((size_t)node << 9) | ((size_t)lane << 4))) = o;
    } else {
        uint lo = ((unsigned)(unsigned short)toBf(vx)) | (((unsigned)(unsigned short)toBf(vy)) << 16);
        uint hi = ((unsigned)(unsigned short)toBf(vz)) | (((unsigned)(unsigned short)toBf(vw)) << 16);
        uint2 ob; ob.x = lo; ob.y = hi;
        *(uint2*)((char*)hnB + nodeOff) = ob;
    }
}

// ---------------- driver ----------------

extern "C" void kernel_launch(void* const* d_in, const int* in_sizes, int n_in,
                              void* d_out, int out_size, void* d_ws, size_t ws_size,
                              hipStream_t stream) {
    const float* x  = (const float*)d_in[0];
    const int*   ei = (const int*)d_in[1];
    const int*   ea = (const int*)d_in[2];
    const float* W  = (const float*)d_in[3];
    const float* nu = (const float*)d_in[4];
    float* out = (float*)d_out;

    int N = in_sizes[0] / DD;
    int E = in_sizes[1] / 2;
    int T = in_sizes[3] / (DD * DD);
    int M = T * N;
    size_t ND = (size_t)N * DD;

    int PSZ = (N + NP - 1) / NP;
    if (PSZ * T > 2048) return;
    if ((long)T * N > (1L << 19)) return;
    int nbA = (E + EB - 1) / EB;
    if (nbA > 512) return;

    size_t reqSerial = sizeof(float) * 2 * (size_t)M
                     + sizeof(ushort) * ((size_t)(4 + T) * ND + (size_t)T * DD * DD)
                     + sizeof(int) * ((size_t)M + 1 + (size_t)E + 64);
    size_t reqEager  = sizeof(float) * 2 * (size_t)M
                     + sizeof(ushort) * ((size_t)(4 + 10) * ND + (size_t)T * DD * DD)
                     + sizeof(int) * ((size_t)M + 1 + (size_t)E + 64);
    if (ws_size < reqSerial) return;
    bool eager = (T == 4) && (ws_size >= reqEager);
    size_t Lslices = eager ? 10 : (size_t)T;

    // workspace layout
    float*  isdS  = (float*)d_ws;            // M f32 (k-major, rsqrt deg_src)
    float*  isdD2 = isdS + M;                // M f32 (dst-major d*T+k, rsqrt deg_dst)
    ushort* xb    = (ushort*)(isdD2 + M);    // ND bf16
    ushort* h1b   = xb + ND;
    ushort* h2b   = h1b + ND;
    ushort* h3b   = h2b + ND;
    ushort* Lr    = h3b + ND;                // product region: 10*ND (eager) or T*ND (serial)
    ushort* WT    = Lr + Lslices * ND;       // T*128*128 bf16
    int* rowptr   = (int*)(WT + (size_t)T * DD * DD);  // M+1
    int* ep       = rowptr + M + 1;          // E
    // setup scratch aliases Lr (setup strictly precedes all product writes)
    int*    binD     = (int*)Lr;                         // E
    ushort* binS     = (ushort*)(binD + E);              // E
    int*    cntB_D   = (int*)(binS + (((size_t)E + 1) & ~(size_t)1));
    int*    cntB_S   = cntB_D + NP * nbA;
    int*    partTotD = cntB_S + NP * nbA;
    int*    partTotS = partTotD + NP;

    size_t scratch = 4 * (size_t)E + 2 * ((size_t)E + 2)
                   + sizeof(int) * (2 * (size_t)NP * nbA + 2 * NP + 16);
    if (scratch > sizeof(ushort) * Lslices * ND) return;

    int totW = T * DD * DD;
    int nPW = (totW + 1023) / 1024;
    int n8 = (int)(ND / 8);
    int nCvt = (n8 + 1023) / 1024;

    kAF<<<nbA + nPW + nCvt, 1024, 0, stream>>>(ei, E, PSZ, nbA, cntB_D, cntB_S,
                                               W, WT, totW, nPW, x, xb, n8);
    kB1<<<2 * NP, 512, 0, stream>>>(cntB_D, cntB_S, nbA, partTotD, partTotS);
    kC<<<nbA, 1024, 0, stream>>>(ei, ea, E, N, T, PSZ, nbA, cntB_D, cntB_S,
                                 partTotD, partTotS, binD, binS);
    kDE<<<2 * NP, 512, 0, stream>>>(binD, binS, partTotD, partTotS,
                                    N, T, PSZ, M, E, rowptr, isdD2, ep, isdS);

    const ushort* histB[4] = {xb, h1b, h2b, h3b};
    int nodeBlocks = ((size_t)N * 32 + 255) / 256;

    if (eager) {
        // layer buffers inside Lr: L_t has t+1 slices; offsets {0,1,3,6} * ND
        ushort* L[4];
        L[0] = Lr;
        L[1] = Lr + 1 * ND;
        L[2] = Lr + 3 * ND;
        L[3] = Lr + 6 * ND;
        int gb128 = (N + 127) / 128;
        for (int t = 0; t < 4; t++) {
            // eager products of hist[t]: P[t][i] -> L[t+i] slice i, for i = 0..3-t
            int nk = 4 - t;
            ushort* d0 = L[t] + 0 * ND;                       // i=0 -> layer t
            ushort* d1 = (nk > 1) ? L[t + 1] + 1 * ND : d0;   // i=1 -> layer t+1
            ushort* d2 = (nk > 2) ? L[t + 2] + 2 * ND : d0;
            ushort* d3 = (nk > 3) ? L[t + 3] + 3 * ND : d0;
            k_gemm_multi<<<gb128, 256, 0, stream>>>(histB[t], WT, isdS,
                                                    d0, d1, d2, d3, nk, N);
            bool lastL = (t == 3);
            k_agg_fin<<<nodeBlocks, 256, 0, stream>>>(L[t], ep, rowptr, isdD2,
                                                      nu, t, T, t + 1, histB[t],
                                                      lastL ? nullptr : (ushort*)histB[t + 1],
                                                      lastL ? out : nullptr, N);
        }
    } else {
        int gb256 = (N + 255) / 256;
        for (int t = 0; t < T; t++) {
            APtrs ap;
            ap.a0 = histB[t];
            ap.a1 = (t >= 1) ? histB[t - 1] : histB[0];
            ap.a2 = (t >= 2) ? histB[t - 2] : histB[0];
            ap.a3 = (t >= 3) ? histB[t - 3] : histB[0];
            dim3 grid(gb256, t + 1);
            k_gemm_batch<<<grid, 256, 0, stream>>>(ap, WT, isdS, Lr, N);
            bool lastL = (t == T - 1);
            k_agg_fin<<<nodeBlocks, 256, 0, stream>>>(Lr, ep, rowptr, isdD2,
                                                      nu, t, T, t + 1, histB[t],
                                                      lastL ? nullptr : (ushort*)histB[t + 1],
                                                      lastL ? out : nullptr, N);
        }
    }
}